// Round 1
// baseline (2447.578 us; speedup 1.0000x reference)
//
#include <hip/hip_runtime.h>
#include <hip/hip_bf16.h>
#include <stdint.h>

#define BB 8
#define CC 64
#define HH 256
#define WW 256
#define NPIX 65536
#define HEADS 4
#define HD 16

using bf16 = __hip_bfloat16;

__device__ __forceinline__ float bf2f(bf16 v) { return __bfloat162float(v); }
__device__ __forceinline__ bf16 f2bf(float v) { return __float2bfloat16(v); }

__device__ __forceinline__ void load8bf(const bf16* p, float* o) {
  uint4 u = *reinterpret_cast<const uint4*>(p);
  o[0] = __uint_as_float(u.x << 16);
  o[1] = __uint_as_float(u.x & 0xffff0000u);
  o[2] = __uint_as_float(u.y << 16);
  o[3] = __uint_as_float(u.y & 0xffff0000u);
  o[4] = __uint_as_float(u.z << 16);
  o[5] = __uint_as_float(u.z & 0xffff0000u);
  o[6] = __uint_as_float(u.w << 16);
  o[7] = __uint_as_float(u.w & 0xffff0000u);
}

// ---------------- kernel: w_cp[c][o][kk] = sum_m w_comp[o][m] * w_proj[m][c][kk]
__global__ void k_wcp(const float* __restrict__ w_comp, const float* __restrict__ w_proj,
                      float* __restrict__ wcp) {
  int idx = blockIdx.x * 256 + threadIdx.x;
  if (idx >= 16 * 64 * 9) return;
  int c = idx / 144;
  int o = (idx % 144) / 9;
  int kk = idx % 9;
  float acc = 0.f;
  for (int m = 0; m < 64; ++m)
    acc += w_comp[o * 64 + m] * w_proj[(m * 64 + c) * 9 + kk];
  wcp[idx] = acc;
}

// ---------------- kernel: fused LayerNorm + 1x1 (q/k/v) + depthwise 3x3
__global__ __launch_bounds__(256)
void k_lnqkv(const float* __restrict__ x,
             const float* __restrict__ ln_w, const float* __restrict__ ln_b,
             const float* __restrict__ w_q, const float* __restrict__ w_k,
             const float* __restrict__ w_v,
             const float* __restrict__ dw_q, const float* __restrict__ dw_k,
             const float* __restrict__ dw_v,
             bf16* __restrict__ qo, bf16* __restrict__ ko, bf16* __restrict__ vo) {
  __shared__ bf16 xn_s[324 * 66];   // [halo pixel][channel], padded stride 66
  __shared__ float pr_s[324 * 65];  // projected tile, padded stride 65
  const int tid = threadIdx.x;
  const int bid = blockIdx.x;
  const int tx = bid & 15, ty = (bid >> 4) & 15, b = bid >> 8;
  const int x0 = tx * 16 - 1, y0 = ty * 16 - 1;
  const float* xb = x + (size_t)b * CC * NPIX;

  // Phase 1: LayerNorm per halo pixel -> LDS (bf16)
  for (int p = tid; p < 324; p += 256) {
    const int py = y0 + p / 18, px = x0 + p % 18;
    if (py < 0 || py >= HH || px < 0 || px >= WW) {
      for (int c = 0; c < CC; ++c) xn_s[p * 66 + c] = f2bf(0.f);
      continue;
    }
    const float* xp = xb + py * WW + px;
    float s = 0.f, s2 = 0.f;
    for (int c = 0; c < CC; ++c) {
      float v = xp[(size_t)c * NPIX];
      s += v; s2 += v * v;
    }
    const float mu = s * (1.f / 64.f);
    const float r = rsqrtf(s2 * (1.f / 64.f) - mu * mu + 1e-6f);
    for (int c = 0; c < CC; ++c) {
      float v = xp[(size_t)c * NPIX];
      xn_s[p * 66 + c] = f2bf((v - mu) * r * ln_w[c] + ln_b[c]);
    }
  }
  __syncthreads();

  for (int t = 0; t < 3; ++t) {
    const float* __restrict__ wm = (t == 0) ? w_q : (t == 1) ? w_k : w_v;
    const float* __restrict__ dm = (t == 0) ? dw_q : (t == 1) ? dw_k : dw_v;
    bf16* __restrict__ ob = ((t == 0) ? qo : (t == 1) ? ko : vo) + (size_t)b * CC * NPIX;

    // 1x1 projection on halo pixels
    for (int p = tid; p < 324; p += 256) {
      float xr[64];
#pragma unroll
      for (int c = 0; c < 64; ++c) xr[c] = bf2f(xn_s[p * 66 + c]);
      for (int o4 = 0; o4 < 64; o4 += 4) {
        float a0 = 0.f, a1 = 0.f, a2 = 0.f, a3 = 0.f;
#pragma unroll
        for (int c = 0; c < 64; ++c) {
          a0 += wm[(o4 + 0) * 64 + c] * xr[c];
          a1 += wm[(o4 + 1) * 64 + c] * xr[c];
          a2 += wm[(o4 + 2) * 64 + c] * xr[c];
          a3 += wm[(o4 + 3) * 64 + c] * xr[c];
        }
        pr_s[p * 65 + o4 + 0] = a0;
        pr_s[p * 65 + o4 + 1] = a1;
        pr_s[p * 65 + o4 + 2] = a2;
        pr_s[p * 65 + o4 + 3] = a3;
      }
    }
    __syncthreads();

    // depthwise 3x3 (cross-correlation, SAME zero pad), one output pixel/thread
    const int oy = tid >> 4, ox = tid & 15;
    const int n = (ty * 16 + oy) * WW + (tx * 16 + ox);
    for (int c = 0; c < 64; ++c) {
      float acc = 0.f;
#pragma unroll
      for (int ky = 0; ky < 3; ++ky)
#pragma unroll
        for (int kx = 0; kx < 3; ++kx)
          acc += dm[c * 9 + ky * 3 + kx] * pr_s[((oy + ky) * 18 + (ox + kx)) * 65 + c];
      ob[(size_t)c * NPIX + n] = f2bf(acc);
    }
    __syncthreads();
  }
}

// ---------------- kernel: sum of squares per (b,c) row for q and k
__global__ __launch_bounds__(256)
void k_sumsq(const bf16* __restrict__ q, const bf16* __restrict__ k,
             float* __restrict__ sqq, float* __restrict__ sqk) {
  const int tid = threadIdx.x;
  const int sel = blockIdx.x >> 9;
  const int bc = blockIdx.x & 511;
  const bf16* p = (sel ? k : q) + (size_t)bc * NPIX;
  float acc = 0.f;
  for (int n = tid * 8; n < NPIX; n += 256 * 8) {
    float a[8];
    load8bf(p + n, a);
#pragma unroll
    for (int u = 0; u < 8; ++u) acc += a[u] * a[u];
  }
  __shared__ float red[256];
  red[tid] = acc;
  __syncthreads();
  for (int s = 128; s > 0; s >>= 1) {
    if (tid < s) red[tid] += red[tid + s];
    __syncthreads();
  }
  if (tid == 0) (sel ? sqk : sqq)[bc] = red[0];
}

// ---------------- kernel: raw logits S[bh][i][j] += sum_n q_i k_j (split over n chunks)
__global__ __launch_bounds__(256)
void k_logits(const bf16* __restrict__ q, const bf16* __restrict__ kk_,
              float* __restrict__ S) {
  const int tid = threadIdx.x;
  const int bh = blockIdx.x >> 5;
  const int chunk = blockIdx.x & 31;
  const int i = tid >> 4, j = tid & 15;
  const bf16* qp = q + (size_t)(bh * HD + i) * NPIX + chunk * 2048;
  const bf16* kp = kk_ + (size_t)(bh * HD + j) * NPIX + chunk * 2048;
  float acc = 0.f;
  for (int n = 0; n < 2048; n += 8) {
    float qa[8], ka[8];
    load8bf(qp + n, qa);
    load8bf(kp + n, ka);
#pragma unroll
    for (int u = 0; u < 8; ++u) acc += qa[u] * ka[u];
  }
  atomicAdd(&S[(size_t)bh * 256 + tid], acc);
}

// ---------------- kernel: normalize logits, temperature, softmax over j
__global__ __launch_bounds__(256)
void k_softmax(const float* __restrict__ S, const float* __restrict__ sqq,
               const float* __restrict__ sqk, const float* __restrict__ temp,
               float* __restrict__ attn) {
  const int tid = threadIdx.x;
  const int bh = blockIdx.x;
  const int i = tid >> 4, j = tid & 15;
  float nq = fmaxf(sqrtf(sqq[bh * HD + i]), 1e-12f);
  float nk = fmaxf(sqrtf(sqk[bh * HD + j]), 1e-12f);
  float val = S[bh * 256 + tid] / (nq * nk) * temp[bh & 3];
  float m = val;
  for (int d = 1; d < 16; d <<= 1) m = fmaxf(m, __shfl_xor(m, d));
  float e = __expf(val - m);
  float s = e;
  for (int d = 1; d < 16; d <<= 1) s += __shfl_xor(s, d);
  attn[bh * 256 + tid] = e / s;
}

// ---------------- kernel: att_out = attn @ v (per pixel)
__global__ __launch_bounds__(256)
void k_attv(const float* __restrict__ attn, const bf16* __restrict__ v,
            bf16* __restrict__ ao) {
  const int tid = threadIdx.x;
  const int bh = blockIdx.x >> 8;
  const int n = ((blockIdx.x & 255) << 8) + tid;
  __shared__ float a_s[256];
  a_s[tid] = attn[bh * 256 + tid];
  __syncthreads();
  const size_t base = (size_t)bh * HD * NPIX;
  float vv[16];
#pragma unroll
  for (int j = 0; j < 16; ++j) vv[j] = bf2f(v[base + (size_t)j * NPIX + n]);
#pragma unroll
  for (int i = 0; i < 16; ++i) {
    float acc = 0.f;
#pragma unroll
    for (int j = 0; j < 16; ++j) acc += a_s[i * 16 + j] * vv[j];
    ao[base + (size_t)i * NPIX + n] = f2bf(acc);
  }
}

// ---------------- kernel: out = conv3x3(att_out, w_cp) + w_comp @ LN(x)
__global__ __launch_bounds__(256)
void k_final(const float* __restrict__ x, const float* __restrict__ ln_w,
             const float* __restrict__ ln_b, const float* __restrict__ w_comp,
             const float* __restrict__ wcp, const bf16* __restrict__ ao,
             float* __restrict__ out) {
  __shared__ bf16 a_s[324 * 66];
  const int tid = threadIdx.x;
  const int bid = blockIdx.x;
  const int tx = bid & 15, ty = (bid >> 4) & 15, b = bid >> 8;
  const int x0 = tx * 16 - 1, y0 = ty * 16 - 1;
  const bf16* ab = ao + (size_t)b * CC * NPIX;
  for (int idx = tid; idx < 64 * 324; idx += 256) {
    const int c = idx / 324, p = idx % 324;
    const int py = y0 + p / 18, px = x0 + p % 18;
    bf16 vv = f2bf(0.f);
    if (py >= 0 && py < HH && px >= 0 && px < WW)
      vv = ab[(size_t)c * NPIX + py * WW + px];
    a_s[p * 66 + c] = vv;
  }
  __syncthreads();
  const int oy = tid >> 4, ox = tid & 15;
  const int n = (ty * 16 + oy) * WW + (tx * 16 + ox);
  const float* xp = x + (size_t)b * CC * NPIX + n;
  float s = 0.f, s2 = 0.f;
  for (int c = 0; c < 64; ++c) {
    float v = xp[(size_t)c * NPIX];
    s += v; s2 += v * v;
  }
  const float mu = s * (1.f / 64.f);
  const float r = rsqrtf(s2 * (1.f / 64.f) - mu * mu + 1e-6f);
  float acc[16];
#pragma unroll
  for (int o = 0; o < 16; ++o) acc[o] = 0.f;
  for (int c = 0; c < 64; ++c) {
    const float xnv = (xp[(size_t)c * NPIX] - mu) * r * ln_w[c] + ln_b[c];
#pragma unroll
    for (int o = 0; o < 16; ++o) acc[o] += w_comp[o * 64 + c] * xnv;
  }
  for (int c = 0; c < 64; ++c) {
    float nb[9];
#pragma unroll
    for (int ky = 0; ky < 3; ++ky)
#pragma unroll
      for (int kx = 0; kx < 3; ++kx)
        nb[ky * 3 + kx] = bf2f(a_s[((oy + ky) * 18 + (ox + kx)) * 66 + c]);
    const float* wc = wcp + c * 144;
#pragma unroll
    for (int o = 0; o < 16; ++o) {
#pragma unroll
      for (int kk = 0; kk < 9; ++kk)
        acc[o] += wc[o * 9 + kk] * nb[kk];
    }
  }
#pragma unroll
  for (int o = 0; o < 16; ++o)
    out[((size_t)b * 16 + o) * NPIX + n] = acc[o];
}

extern "C" void kernel_launch(void* const* d_in, const int* in_sizes, int n_in,
                              void* d_out, int out_size, void* d_ws, size_t ws_size,
                              hipStream_t stream) {
  const float* x      = (const float*)d_in[0];
  const float* ln_w   = (const float*)d_in[1];
  const float* ln_b   = (const float*)d_in[2];
  const float* w_q    = (const float*)d_in[3];
  const float* w_k    = (const float*)d_in[4];
  const float* w_v    = (const float*)d_in[5];
  const float* dw_q   = (const float*)d_in[6];
  const float* dw_k   = (const float*)d_in[7];
  const float* dw_v   = (const float*)d_in[8];
  const float* w_proj = (const float*)d_in[9];
  const float* w_comp = (const float*)d_in[10];
  const float* temp   = (const float*)d_in[11];
  float* out = (float*)d_out;

  const size_t TEN = (size_t)BB * CC * NPIX;  // 33,554,432 elements
  bf16* qb = (bf16*)d_ws;          // 64 MB (later reused as att_out)
  bf16* kb = qb + TEN;             // 64 MB
  bf16* vb = kb + TEN;             // 64 MB
  float* wcp = (float*)(vb + TEN); // 9216 floats, layout [c][o][3*3]
  float* sqq = wcp + 16 * 64 * 9;  // 512
  float* sqk = sqq + 512;          // 512
  float* S   = sqk + 512;          // 8192
  float* attn = S + 8192;          // 8192

  hipMemsetAsync(S, 0, 8192 * sizeof(float), stream);
  k_wcp<<<36, 256, 0, stream>>>(w_comp, w_proj, wcp);
  k_lnqkv<<<2048, 256, 0, stream>>>(x, ln_w, ln_b, w_q, w_k, w_v,
                                    dw_q, dw_k, dw_v, qb, kb, vb);
  k_sumsq<<<1024, 256, 0, stream>>>(qb, kb, sqq, sqk);
  k_logits<<<1024, 256, 0, stream>>>(qb, kb, S);
  k_softmax<<<32, 256, 0, stream>>>(S, sqq, sqk, temp, attn);
  k_attv<<<8192, 256, 0, stream>>>(attn, vb, qb);
  k_final<<<2048, 256, 0, stream>>>(x, ln_w, ln_b, w_comp, wcp, qb, out);
}

// Round 3
// 756.158 us; speedup vs baseline: 3.2369x; 3.2369x over previous
//
#include <hip/hip_runtime.h>
#include <hip/hip_bf16.h>
#include <stdint.h>

#define BB 8
#define CC 64
#define HH 256
#define WW 256
#define NPIX 65536
#define HEADS 4
#define HD 16

using bf16 = __hip_bfloat16;
typedef __attribute__((ext_vector_type(8))) short short8;
typedef __attribute__((ext_vector_type(4))) float f32x4;

__device__ __forceinline__ float bf2f(bf16 v) { return __bfloat162float(v); }
__device__ __forceinline__ bf16 f2bf(float v) { return __float2bfloat16(v); }
__device__ __forceinline__ short f2bfs(float f) { bf16 h = __float2bfloat16(f); return *reinterpret_cast<short*>(&h); }
__device__ __forceinline__ float bfs2f(short s) { return __uint_as_float(((uint32_t)(uint16_t)s) << 16); }

__device__ __forceinline__ void load8bf(const bf16* p, float* o) {
  uint4 u = *reinterpret_cast<const uint4*>(p);
  o[0] = __uint_as_float(u.x << 16);
  o[1] = __uint_as_float(u.x & 0xffff0000u);
  o[2] = __uint_as_float(u.y << 16);
  o[3] = __uint_as_float(u.y & 0xffff0000u);
  o[4] = __uint_as_float(u.z << 16);
  o[5] = __uint_as_float(u.z & 0xffff0000u);
  o[6] = __uint_as_float(u.w << 16);
  o[7] = __uint_as_float(u.w & 0xffff0000u);
}

// ---------------- kernel: w_cp[c][o][kk] = sum_m w_comp[o][m] * w_proj[m][c][kk]
__global__ void k_wcp(const float* __restrict__ w_comp, const float* __restrict__ w_proj,
                      float* __restrict__ wcp) {
  int idx = blockIdx.x * 256 + threadIdx.x;
  if (idx >= 16 * 64 * 9) return;
  int c = idx / 144;
  int o = (idx % 144) / 9;
  int kk = idx % 9;
  float acc = 0.f;
  for (int m = 0; m < 64; ++m)
    acc += w_comp[o * 64 + m] * w_proj[(m * 64 + c) * 9 + kk];
  wcp[idx] = acc;
}

// ---------------- fused LayerNorm + 1x1 (MFMA) + depthwise 3x3
__global__ __launch_bounds__(512, 2)
void k_lnqkv(const float* __restrict__ x,
             const float* __restrict__ ln_w, const float* __restrict__ ln_b,
             const float* __restrict__ w_q, const float* __restrict__ w_k,
             const float* __restrict__ w_v,
             const float* __restrict__ dw_q, const float* __restrict__ dw_k,
             const float* __restrict__ dw_v,
             bf16* __restrict__ qo, bf16* __restrict__ ko, bf16* __restrict__ vo) {
  __shared__ short xn_s[336 * 72];  // LN'd input, [halo pix][64ch]
  __shared__ short pr_s[336 * 72];  // 1x1 output, [halo pix][64 outch]
  __shared__ short w_s[192 * 72];   // bf16 weights, [t*64+o][64c]
  const int tid = threadIdx.x;
  const int lane = tid & 63;
  const int wv = tid >> 6;          // wave 0..7
  const int olocal = lane & 15;
  const int g = lane >> 4;          // 0..3
  const int tx = blockIdx.x & 15, ty = (blockIdx.x >> 4) & 15, b = blockIdx.x >> 8;

  // stage weights as bf16 into LDS
  {
    const float* Ws[3] = {w_q, w_k, w_v};
    for (int it = tid; it < 1536; it += 512) {
      int row = it >> 3, c8 = it & 7;
      int t = row >> 6, o = row & 63;
      const float* wp = Ws[t] + o * 64 + c8 * 8;
      uint32_t pk[4];
#pragma unroll
      for (int j = 0; j < 4; ++j) {
        uint32_t lo = (uint32_t)(uint16_t)f2bfs(wp[2 * j]);
        uint32_t hi = (uint32_t)(uint16_t)f2bfs(wp[2 * j + 1]);
        pk[j] = lo | (hi << 16);
      }
      *reinterpret_cast<uint4*>(&w_s[row * 72 + c8 * 8]) = make_uint4(pk[0], pk[1], pk[2], pk[3]);
    }
  }

  // LayerNorm phase: one thread per halo pixel
  if (tid < 336) {
    const int p = tid;
    bool valid = false;
    int py = 0, px = 0;
    if (p < 324) {
      py = ty * 16 - 1 + p / 18;
      px = tx * 16 - 1 + p % 18;
      valid = (py >= 0 && py < HH && px >= 0 && px < WW);
    }
    if (valid) {
      const float* xp = x + (size_t)b * CC * NPIX + py * WW + px;
      float v[64];
      float s = 0.f, s2 = 0.f;
#pragma unroll
      for (int c = 0; c < 64; ++c) { float t0 = xp[(size_t)c * NPIX]; v[c] = t0; s += t0; s2 += t0 * t0; }
      const float mu = s * (1.f / 64.f);
      const float r = rsqrtf(s2 * (1.f / 64.f) - mu * mu + 1e-6f);
#pragma unroll
      for (int c8 = 0; c8 < 8; ++c8) {
        uint32_t pk[4];
#pragma unroll
        for (int j = 0; j < 4; ++j) {
          const int c0 = c8 * 8 + 2 * j;
          float f0 = (v[c0] - mu) * r * ln_w[c0] + ln_b[c0];
          float f1 = (v[c0 + 1] - mu) * r * ln_w[c0 + 1] + ln_b[c0 + 1];
          pk[j] = (uint32_t)(uint16_t)f2bfs(f0) | ((uint32_t)(uint16_t)f2bfs(f1) << 16);
        }
        *reinterpret_cast<uint4*>(&xn_s[p * 72 + c8 * 8]) = make_uint4(pk[0], pk[1], pk[2], pk[3]);
      }
    } else {
      const uint4 z = make_uint4(0, 0, 0, 0);
#pragma unroll
      for (int c8 = 0; c8 < 8; ++c8)
        *reinterpret_cast<uint4*>(&xn_s[p * 72 + c8 * 8]) = z;
    }
  }
  __syncthreads();

  for (int t = 0; t < 3; ++t) {
    if (t) __syncthreads();  // pr_s free from previous iteration's phase3
    short8 Bt[4][2];
#pragma unroll
    for (int ot = 0; ot < 4; ++ot) {
      const short* wb = &w_s[(t * 64 + ot * 16 + olocal) * 72 + g * 8];
      Bt[ot][0] = *reinterpret_cast<const short8*>(wb);
      Bt[ot][1] = *reinterpret_cast<const short8*>(wb + 32);
    }
    // phase2: 1x1 projection via MFMA, 21 pixel-tiles of 16
    for (int pt = wv; pt < 21; pt += 8) {
      const short* ab = &xn_s[(pt * 16 + olocal) * 72 + g * 8];
      short8 a0 = *reinterpret_cast<const short8*>(ab);
      short8 a1 = *reinterpret_cast<const short8*>(ab + 32);
#pragma unroll
      for (int ot = 0; ot < 4; ++ot) {
        f32x4 acc = {0.f, 0.f, 0.f, 0.f};
        acc = __builtin_amdgcn_mfma_f32_16x16x32_bf16(a0, Bt[ot][0], acc, 0, 0, 0);
        acc = __builtin_amdgcn_mfma_f32_16x16x32_bf16(a1, Bt[ot][1], acc, 0, 0, 0);
#pragma unroll
        for (int r = 0; r < 4; ++r)
          pr_s[(pt * 16 + g * 4 + r) * 72 + ot * 16 + olocal] = f2bfs(acc[r]);
      }
    }
    __syncthreads();
    // phase3: depthwise 3x3; wave wv owns channels wv*8..wv*8+8
    const float* dmt = (t == 0) ? dw_q : (t == 1) ? dw_k : dw_v;
    bf16* ob = ((t == 0) ? qo : (t == 1) ? ko : vo) + (size_t)b * CC * NPIX;
    float dmr[8][9];
#pragma unroll
    for (int u = 0; u < 8; ++u)
#pragma unroll
      for (int kk = 0; kk < 9; ++kk)
        dmr[u][kk] = dmt[(wv * 8 + u) * 9 + kk];
#pragma unroll
    for (int i = 0; i < 4; ++i) {
      const int pxl = lane + i * 64;
      const int oy = pxl >> 4, ox = pxl & 15;
      float acc8[8] = {0.f, 0.f, 0.f, 0.f, 0.f, 0.f, 0.f, 0.f};
#pragma unroll
      for (int ky = 0; ky < 3; ++ky)
#pragma unroll
        for (int kx = 0; kx < 3; ++kx) {
          const short8 pv = *reinterpret_cast<const short8*>(
              &pr_s[((oy + ky) * 18 + ox + kx) * 72 + wv * 8]);
          const int kk = ky * 3 + kx;
#pragma unroll
          for (int u = 0; u < 8; ++u)
            acc8[u] += dmr[u][kk] * bfs2f(pv[u]);
        }
      const int n = (ty * 16 + oy) * WW + tx * 16 + ox;
#pragma unroll
      for (int u = 0; u < 8; ++u)
        ob[(size_t)(wv * 8 + u) * NPIX + n] = f2bf(acc8[u]);
    }
  }
}

// ---------------- kernel: sum of squares per (b,c) row for q and k
__global__ __launch_bounds__(256)
void k_sumsq(const bf16* __restrict__ q, const bf16* __restrict__ k,
             float* __restrict__ sqq, float* __restrict__ sqk) {
  const int tid = threadIdx.x;
  const int sel = blockIdx.x >> 9;
  const int bc = blockIdx.x & 511;
  const bf16* p = (sel ? k : q) + (size_t)bc * NPIX;
  float acc = 0.f;
  for (int n = tid * 8; n < NPIX; n += 256 * 8) {
    float a[8];
    load8bf(p + n, a);
#pragma unroll
    for (int u = 0; u < 8; ++u) acc += a[u] * a[u];
  }
  __shared__ float red[256];
  red[tid] = acc;
  __syncthreads();
  for (int s = 128; s > 0; s >>= 1) {
    if (tid < s) red[tid] += red[tid + s];
    __syncthreads();
  }
  if (tid == 0) (sel ? sqk : sqq)[bc] = red[0];
}

// ---------------- kernel: deterministic partial logits
// Spart[(bh*8 + chunk)*256 + i*16 + j] = sum over this chunk's 8192 pixels of q_i * k_j
__global__ __launch_bounds__(256)
void k_logits(const bf16* __restrict__ q, const bf16* __restrict__ kk_,
              float* __restrict__ Spart) {
  const int tid = threadIdx.x;
  const int bh = blockIdx.x >> 3;
  const int chunk = blockIdx.x & 7;
  const int i = tid >> 4, j = tid & 15;
  const bf16* qp = q + (size_t)(bh * HD + i) * NPIX + chunk * 8192;
  const bf16* kp = kk_ + (size_t)(bh * HD + j) * NPIX + chunk * 8192;
  float acc = 0.f;
  for (int n = 0; n < 8192; n += 8) {
    float qa[8], ka[8];
    load8bf(qp + n, qa);
    load8bf(kp + n, ka);
#pragma unroll
    for (int u = 0; u < 8; ++u) acc += qa[u] * ka[u];
  }
  Spart[(size_t)blockIdx.x * 256 + tid] = acc;
}

// ---------------- kernel: reduce partials, normalize, temperature, softmax over j
__global__ __launch_bounds__(256)
void k_softmax(const float* __restrict__ Spart, const float* __restrict__ sqq,
               const float* __restrict__ sqk, const float* __restrict__ temp,
               float* __restrict__ attn) {
  const int tid = threadIdx.x;
  const int bh = blockIdx.x;
  const int i = tid >> 4, j = tid & 15;
  float S = 0.f;
#pragma unroll
  for (int c = 0; c < 8; ++c)
    S += Spart[(size_t)(bh * 8 + c) * 256 + tid];
  float nq = fmaxf(sqrtf(sqq[bh * HD + i]), 1e-12f);
  float nk = fmaxf(sqrtf(sqk[bh * HD + j]), 1e-12f);
  float val = S / (nq * nk) * temp[bh & 3];
  float m = val;
  for (int d = 1; d < 16; d <<= 1) m = fmaxf(m, __shfl_xor(m, d));
  float e = __expf(val - m);
  float s = e;
  for (int d = 1; d < 16; d <<= 1) s += __shfl_xor(s, d);
  attn[bh * 256 + tid] = e / s;
}

// ---------------- kernel: att_out = attn @ v (per pixel)
__global__ __launch_bounds__(256)
void k_attv(const float* __restrict__ attn, const bf16* __restrict__ v,
            bf16* __restrict__ ao) {
  const int tid = threadIdx.x;
  const int bh = blockIdx.x >> 8;
  const int n = ((blockIdx.x & 255) << 8) + tid;
  __shared__ float a_s[256];
  a_s[tid] = attn[bh * 256 + tid];
  __syncthreads();
  const size_t base = (size_t)bh * HD * NPIX;
  float vv[16];
#pragma unroll
  for (int j = 0; j < 16; ++j) vv[j] = bf2f(v[base + (size_t)j * NPIX + n]);
#pragma unroll
  for (int i = 0; i < 16; ++i) {
    float acc = 0.f;
#pragma unroll
    for (int j = 0; j < 16; ++j) acc += a_s[i * 16 + j] * vv[j];
    ao[base + (size_t)i * NPIX + n] = f2bf(acc);
  }
}

// ---------------- kernel: out = conv3x3(att_out, w_cp) + w_comp @ LN(x)
__global__ __launch_bounds__(256)
void k_final(const float* __restrict__ x, const float* __restrict__ ln_w,
             const float* __restrict__ ln_b, const float* __restrict__ w_comp,
             const float* __restrict__ wcp, const bf16* __restrict__ ao,
             float* __restrict__ out) {
  __shared__ bf16 a_s[324 * 66];
  const int tid = threadIdx.x;
  const int bid = blockIdx.x;
  const int tx = bid & 15, ty = (bid >> 4) & 15, b = bid >> 8;
  const int x0 = tx * 16 - 1, y0 = ty * 16 - 1;
  const bf16* ab = ao + (size_t)b * CC * NPIX;
  for (int idx = tid; idx < 64 * 324; idx += 256) {
    const int c = idx / 324, p = idx % 324;
    const int py = y0 + p / 18, px = x0 + p % 18;
    bf16 vv = f2bf(0.f);
    if (py >= 0 && py < HH && px >= 0 && px < WW)
      vv = ab[(size_t)c * NPIX + py * WW + px];
    a_s[p * 66 + c] = vv;
  }
  __syncthreads();
  const int oy = tid >> 4, ox = tid & 15;
  const int n = (ty * 16 + oy) * WW + (tx * 16 + ox);
  const float* xp = x + (size_t)b * CC * NPIX + n;
  float s = 0.f, s2 = 0.f;
  for (int c = 0; c < 64; ++c) {
    float v = xp[(size_t)c * NPIX];
    s += v; s2 += v * v;
  }
  const float mu = s * (1.f / 64.f);
  const float r = rsqrtf(s2 * (1.f / 64.f) - mu * mu + 1e-6f);
  float acc[16];
#pragma unroll
  for (int o = 0; o < 16; ++o) acc[o] = 0.f;
  for (int c = 0; c < 64; ++c) {
    const float xnv = (xp[(size_t)c * NPIX] - mu) * r * ln_w[c] + ln_b[c];
#pragma unroll
    for (int o = 0; o < 16; ++o) acc[o] += w_comp[o * 64 + c] * xnv;
  }
  for (int c = 0; c < 64; ++c) {
    float nb[9];
#pragma unroll
    for (int ky = 0; ky < 3; ++ky)
#pragma unroll
      for (int kx = 0; kx < 3; ++kx)
        nb[ky * 3 + kx] = bf2f(a_s[((oy + ky) * 18 + (ox + kx)) * 66 + c]);
    const float* wc = wcp + c * 144;
#pragma unroll
    for (int o = 0; o < 16; ++o) {
#pragma unroll
      for (int kk = 0; kk < 9; ++kk)
        acc[o] += wc[o * 9 + kk] * nb[kk];
    }
  }
#pragma unroll
  for (int o = 0; o < 16; ++o)
    out[((size_t)b * 16 + o) * NPIX + n] = acc[o];
}

extern "C" void kernel_launch(void* const* d_in, const int* in_sizes, int n_in,
                              void* d_out, int out_size, void* d_ws, size_t ws_size,
                              hipStream_t stream) {
  const float* x      = (const float*)d_in[0];
  const float* ln_w   = (const float*)d_in[1];
  const float* ln_b   = (const float*)d_in[2];
  const float* w_q    = (const float*)d_in[3];
  const float* w_k    = (const float*)d_in[4];
  const float* w_v    = (const float*)d_in[5];
  const float* dw_q   = (const float*)d_in[6];
  const float* dw_k   = (const float*)d_in[7];
  const float* dw_v   = (const float*)d_in[8];
  const float* w_proj = (const float*)d_in[9];
  const float* w_comp = (const float*)d_in[10];
  const float* temp   = (const float*)d_in[11];
  float* out = (float*)d_out;

  const size_t TEN = (size_t)BB * CC * NPIX;  // 33,554,432 elements
  bf16* qb = (bf16*)d_ws;          // 64 MB (later reused as att_out)
  bf16* kb = qb + TEN;             // 64 MB
  bf16* vb = kb + TEN;             // 64 MB
  float* wcp = (float*)(vb + TEN); // 9216 floats, layout [c][o][3*3]
  float* sqq = wcp + 16 * 64 * 9;  // 512
  float* sqk = sqq + 512;          // 512
  float* Spart = sqk + 512;        // 32*8*256 = 65536 floats
  float* attn = Spart + 65536;     // 8192

  k_wcp<<<36, 256, 0, stream>>>(w_comp, w_proj, wcp);
  k_lnqkv<<<2048, 512, 0, stream>>>(x, ln_w, ln_b, w_q, w_k, w_v,
                                    dw_q, dw_k, dw_v, qb, kb, vb);
  k_sumsq<<<1024, 256, 0, stream>>>(qb, kb, sqq, sqk);
  k_logits<<<256, 256, 0, stream>>>(qb, kb, Spart);
  k_softmax<<<32, 256, 0, stream>>>(Spart, sqq, sqk, temp, attn);
  k_attv<<<8192, 256, 0, stream>>>(attn, vb, qb);
  k_final<<<2048, 256, 0, stream>>>(x, ln_w, ln_b, w_comp, wcp, qb, out);
}

// Round 4
// 621.098 us; speedup vs baseline: 3.9407x; 1.2175x over previous
//
#include <hip/hip_runtime.h>
#include <hip/hip_bf16.h>
#include <stdint.h>

#define BB 8
#define CC 64
#define HH 256
#define WW 256
#define NPIX 65536
#define HEADS 4
#define HD 16

using bf16 = __hip_bfloat16;
typedef __attribute__((ext_vector_type(8))) short short8;
typedef __attribute__((ext_vector_type(4))) float f32x4;

__device__ __forceinline__ float bf2f(bf16 v) { return __bfloat162float(v); }
__device__ __forceinline__ bf16 f2bf(float v) { return __float2bfloat16(v); }
__device__ __forceinline__ short f2bfs(float f) { bf16 h = __float2bfloat16(f); return *reinterpret_cast<short*>(&h); }
__device__ __forceinline__ float bfs2f(short s) { return __uint_as_float(((uint32_t)(uint16_t)s) << 16); }
__device__ __forceinline__ uint32_t pk2(float a, float b) {
  return (uint32_t)(uint16_t)f2bfs(a) | ((uint32_t)(uint16_t)f2bfs(b) << 16);
}
__device__ __forceinline__ short8 zero8() { short8 z = {0, 0, 0, 0, 0, 0, 0, 0}; return z; }

__device__ __forceinline__ void load8bf(const bf16* p, float* o) {
  uint4 u = *reinterpret_cast<const uint4*>(p);
  o[0] = __uint_as_float(u.x << 16);
  o[1] = __uint_as_float(u.x & 0xffff0000u);
  o[2] = __uint_as_float(u.y << 16);
  o[3] = __uint_as_float(u.y & 0xffff0000u);
  o[4] = __uint_as_float(u.z << 16);
  o[5] = __uint_as_float(u.z & 0xffff0000u);
  o[6] = __uint_as_float(u.w << 16);
  o[7] = __uint_as_float(u.w & 0xffff0000u);
}

// ---------------- kernel: wcpb[kk][o][c] = bf16( sum_m w_comp[o][m] * w_proj[m][c][kk] )
__global__ void k_wcp(const float* __restrict__ w_comp, const float* __restrict__ w_proj,
                      short* __restrict__ wcpb) {
  int idx = blockIdx.x * 256 + threadIdx.x;
  if (idx >= 9 * 16 * 64) return;
  int c = idx & 63;
  int o = (idx >> 6) & 15;
  int kk = idx >> 10;
  float acc = 0.f;
  for (int m = 0; m < 64; ++m)
    acc += w_comp[o * 64 + m] * w_proj[(m * 64 + c) * 9 + kk];
  wcpb[idx] = f2bfs(acc);
}

// ---------------- fused LayerNorm + 1x1 (MFMA) + depthwise 3x3 + residual-compress
__global__ __launch_bounds__(512, 2)
void k_lnqkv(const float* __restrict__ x,
             const float* __restrict__ ln_w, const float* __restrict__ ln_b,
             const float* __restrict__ w_q, const float* __restrict__ w_k,
             const float* __restrict__ w_v,
             const float* __restrict__ dw_q, const float* __restrict__ dw_k,
             const float* __restrict__ dw_v,
             const float* __restrict__ w_comp,
             bf16* __restrict__ qo, bf16* __restrict__ ko, bf16* __restrict__ vo,
             short* __restrict__ res16) {
  __shared__ short xn_s[336 * 72];  // LN'd input, [halo pix][64ch]
  __shared__ short pr_s[336 * 72];  // 1x1 output, [halo pix][64 outch]
  __shared__ short w_s[192 * 72];   // bf16 weights, [t*64+o][64c]
  const int tid = threadIdx.x;
  const int lane = tid & 63;
  const int wv = tid >> 6;          // wave 0..7
  const int olocal = lane & 15;
  const int g = lane >> 4;          // 0..3
  const int tx = blockIdx.x & 15, ty = (blockIdx.x >> 4) & 15, b = blockIdx.x >> 8;

  // stage weights as bf16 into LDS
  {
    const float* Ws[3] = {w_q, w_k, w_v};
    for (int it = tid; it < 1536; it += 512) {
      int row = it >> 3, c8 = it & 7;
      int t = row >> 6, o = row & 63;
      const float* wp = Ws[t] + o * 64 + c8 * 8;
      uint32_t pk[4];
#pragma unroll
      for (int j = 0; j < 4; ++j) pk[j] = pk2(wp[2 * j], wp[2 * j + 1]);
      *reinterpret_cast<uint4*>(&w_s[row * 72 + c8 * 8]) = make_uint4(pk[0], pk[1], pk[2], pk[3]);
    }
  }

  // LayerNorm phase: one thread per halo pixel
  if (tid < 336) {
    const int p = tid;
    bool valid = false;
    int py = 0, px = 0;
    if (p < 324) {
      py = ty * 16 - 1 + p / 18;
      px = tx * 16 - 1 + p % 18;
      valid = (py >= 0 && py < HH && px >= 0 && px < WW);
    }
    if (valid) {
      const float* xp = x + (size_t)b * CC * NPIX + py * WW + px;
      float v[64];
      float s = 0.f, s2 = 0.f;
#pragma unroll
      for (int c = 0; c < 64; ++c) { float t0 = xp[(size_t)c * NPIX]; v[c] = t0; s += t0; s2 += t0 * t0; }
      const float mu = s * (1.f / 64.f);
      const float r = rsqrtf(s2 * (1.f / 64.f) - mu * mu + 1e-6f);
#pragma unroll
      for (int c8 = 0; c8 < 8; ++c8) {
        uint32_t pk[4];
#pragma unroll
        for (int j = 0; j < 4; ++j) {
          const int c0 = c8 * 8 + 2 * j;
          float f0 = (v[c0] - mu) * r * ln_w[c0] + ln_b[c0];
          float f1 = (v[c0 + 1] - mu) * r * ln_w[c0 + 1] + ln_b[c0 + 1];
          pk[j] = pk2(f0, f1);
        }
        *reinterpret_cast<uint4*>(&xn_s[p * 72 + c8 * 8]) = make_uint4(pk[0], pk[1], pk[2], pk[3]);
      }
    } else {
      const uint4 z = make_uint4(0, 0, 0, 0);
#pragma unroll
      for (int c8 = 0; c8 < 8; ++c8)
        *reinterpret_cast<uint4*>(&xn_s[p * 72 + c8 * 8]) = z;
    }
  }
  __syncthreads();

  // residual-compress: res16[b][n][o16] = w_comp @ xn, via MFMA (D rows=o, cols=px)
  {
    short8 wc0, wc1;
    const float* wp = w_comp + olocal * 64 + g * 8;
#pragma unroll
    for (int j = 0; j < 8; ++j) { wc0[j] = f2bfs(wp[j]); wc1[j] = f2bfs(wp[32 + j]); }
#pragma unroll
    for (int t2 = 0; t2 < 2; ++t2) {
      const int oy = wv * 2 + t2;  // 0..15
      const short* bb = &xn_s[((oy + 1) * 18 + 1 + olocal) * 72 + g * 8];
      short8 b0 = *reinterpret_cast<const short8*>(bb);
      short8 b1 = *reinterpret_cast<const short8*>(bb + 32);
      f32x4 acc = {0.f, 0.f, 0.f, 0.f};
      acc = __builtin_amdgcn_mfma_f32_16x16x32_bf16(wc0, b0, acc, 0, 0, 0);
      acc = __builtin_amdgcn_mfma_f32_16x16x32_bf16(wc1, b1, acc, 0, 0, 0);
      const int n = (ty * 16 + oy) * WW + tx * 16 + olocal;
      uint2 st;
      st.x = pk2(acc[0], acc[1]);
      st.y = pk2(acc[2], acc[3]);
      *reinterpret_cast<uint2*>(&res16[((size_t)b * NPIX + n) * 16 + g * 4]) = st;
    }
  }

  for (int t = 0; t < 3; ++t) {
    if (t) __syncthreads();  // pr_s free from previous iteration's phase3
    short8 Bt[4][2];
#pragma unroll
    for (int ot = 0; ot < 4; ++ot) {
      const short* wb = &w_s[(t * 64 + ot * 16 + olocal) * 72 + g * 8];
      Bt[ot][0] = *reinterpret_cast<const short8*>(wb);
      Bt[ot][1] = *reinterpret_cast<const short8*>(wb + 32);
    }
    // phase2: 1x1 projection via MFMA, 21 pixel-tiles of 16
    for (int pt = wv; pt < 21; pt += 8) {
      const short* ab = &xn_s[(pt * 16 + olocal) * 72 + g * 8];
      short8 a0 = *reinterpret_cast<const short8*>(ab);
      short8 a1 = *reinterpret_cast<const short8*>(ab + 32);
#pragma unroll
      for (int ot = 0; ot < 4; ++ot) {
        f32x4 acc = {0.f, 0.f, 0.f, 0.f};
        acc = __builtin_amdgcn_mfma_f32_16x16x32_bf16(a0, Bt[ot][0], acc, 0, 0, 0);
        acc = __builtin_amdgcn_mfma_f32_16x16x32_bf16(a1, Bt[ot][1], acc, 0, 0, 0);
#pragma unroll
        for (int r = 0; r < 4; ++r)
          pr_s[(pt * 16 + g * 4 + r) * 72 + ot * 16 + olocal] = f2bfs(acc[r]);
      }
    }
    __syncthreads();
    // phase3: depthwise 3x3; wave wv owns channels wv*8..wv*8+8
    const float* dmt = (t == 0) ? dw_q : (t == 1) ? dw_k : dw_v;
    bf16* ob = ((t == 0) ? qo : (t == 1) ? ko : vo) + (size_t)b * CC * NPIX;
    float dmr[8][9];
#pragma unroll
    for (int u = 0; u < 8; ++u)
#pragma unroll
      for (int kk = 0; kk < 9; ++kk)
        dmr[u][kk] = dmt[(wv * 8 + u) * 9 + kk];
#pragma unroll
    for (int i = 0; i < 4; ++i) {
      const int pxl = lane + i * 64;
      const int oy = pxl >> 4, ox = pxl & 15;
      float acc8[8] = {0.f, 0.f, 0.f, 0.f, 0.f, 0.f, 0.f, 0.f};
#pragma unroll
      for (int ky = 0; ky < 3; ++ky)
#pragma unroll
        for (int kx = 0; kx < 3; ++kx) {
          const short8 pv = *reinterpret_cast<const short8*>(
              &pr_s[((oy + ky) * 18 + ox + kx) * 72 + wv * 8]);
          const int kk = ky * 3 + kx;
#pragma unroll
          for (int u = 0; u < 8; ++u)
            acc8[u] += dmr[u][kk] * bfs2f(pv[u]);
        }
      const int n = (ty * 16 + oy) * WW + tx * 16 + ox;
#pragma unroll
      for (int u = 0; u < 8; ++u)
        ob[(size_t)(wv * 8 + u) * NPIX + n] = f2bf(acc8[u]);
    }
  }
}

// ---------------- kernel: partial logits + diagonal sumsq (deterministic, no atomics)
__global__ __launch_bounds__(256)
void k_logits(const bf16* __restrict__ q, const bf16* __restrict__ kk_,
              float* __restrict__ Spart, float* __restrict__ Qpart,
              float* __restrict__ Kpart) {
  const int tid = threadIdx.x;
  const int bh = blockIdx.x >> 3;
  const int chunk = blockIdx.x & 7;
  const int i = tid >> 4, j = tid & 15;
  const bf16* qp = q + (size_t)(bh * HD + i) * NPIX + chunk * 8192;
  const bf16* kp = kk_ + (size_t)(bh * HD + j) * NPIX + chunk * 8192;
  float acc = 0.f, accq = 0.f, acck = 0.f;
  const bool diag = (i == j);
  for (int n = 0; n < 8192; n += 8) {
    float qa[8], ka[8];
    load8bf(qp + n, qa);
    load8bf(kp + n, ka);
#pragma unroll
    for (int u = 0; u < 8; ++u) acc += qa[u] * ka[u];
    if (diag) {
#pragma unroll
      for (int u = 0; u < 8; ++u) { accq += qa[u] * qa[u]; acck += ka[u] * ka[u]; }
    }
  }
  Spart[(size_t)blockIdx.x * 256 + tid] = acc;
  if (diag) {
    Qpart[(size_t)blockIdx.x * 16 + i] = accq;
    Kpart[(size_t)blockIdx.x * 16 + i] = acck;
  }
}

// ---------------- kernel: reduce partials, normalize, temperature, softmax over j
__global__ __launch_bounds__(256)
void k_softmax(const float* __restrict__ Spart, const float* __restrict__ Qpart,
               const float* __restrict__ Kpart, const float* __restrict__ temp,
               float* __restrict__ attn) {
  const int tid = threadIdx.x;
  const int bh = blockIdx.x;
  const int i = tid >> 4, j = tid & 15;
  float S = 0.f, qs = 0.f, ks = 0.f;
#pragma unroll
  for (int c = 0; c < 8; ++c) {
    S += Spart[(size_t)(bh * 8 + c) * 256 + tid];
    qs += Qpart[(size_t)(bh * 8 + c) * 16 + i];
    ks += Kpart[(size_t)(bh * 8 + c) * 16 + j];
  }
  float nq = fmaxf(sqrtf(qs), 1e-12f);
  float nk = fmaxf(sqrtf(ks), 1e-12f);
  float val = S / (nq * nk) * temp[bh & 3];
  float m = val;
  for (int d = 1; d < 16; d <<= 1) m = fmaxf(m, __shfl_xor(m, d));
  float e = __expf(val - m);
  float s = e;
  for (int d = 1; d < 16; d <<= 1) s += __shfl_xor(s, d);
  attn[bh * 256 + tid] = e / s;
}

// ---------------- kernel: att_out = attn @ v, written PIXEL-MAJOR [b][n][64]
__global__ __launch_bounds__(256)
void k_attv(const float* __restrict__ attn, const bf16* __restrict__ v,
            bf16* __restrict__ aopm) {
  const int tid = threadIdx.x;
  const int bh = blockIdx.x >> 8;
  const int b = bh >> 2, h = bh & 3;
  const int n = ((blockIdx.x & 255) << 8) + tid;
  __shared__ float a_s[256];
  a_s[tid] = attn[bh * 256 + tid];
  __syncthreads();
  const size_t base = (size_t)bh * HD * NPIX;
  float vv[16];
#pragma unroll
  for (int j = 0; j < 16; ++j) vv[j] = bf2f(v[base + (size_t)j * NPIX + n]);
  float o[16];
#pragma unroll
  for (int i = 0; i < 16; ++i) {
    float acc = 0.f;
#pragma unroll
    for (int j = 0; j < 16; ++j) acc += a_s[i * 16 + j] * vv[j];
    o[i] = acc;
  }
  uint4 lo = make_uint4(pk2(o[0], o[1]), pk2(o[2], o[3]), pk2(o[4], o[5]), pk2(o[6], o[7]));
  uint4 hi = make_uint4(pk2(o[8], o[9]), pk2(o[10], o[11]), pk2(o[12], o[13]), pk2(o[14], o[15]));
  short* op = (short*)aopm + ((size_t)b * NPIX + n) * 64 + h * 16;
  *reinterpret_cast<uint4*>(op) = lo;
  *reinterpret_cast<uint4*>(op + 8) = hi;
}

// ---------------- kernel: out = conv3x3(ao, wcp) + res16, pure MFMA, no LDS
__global__ __launch_bounds__(256)
void k_final(const short* __restrict__ wcpb, const bf16* __restrict__ aopm,
             const short* __restrict__ res16, float* __restrict__ out) {
  const int tid = threadIdx.x;
  const int lane = tid & 63;
  const int wv = tid >> 6;          // 0..3
  const int olocal = lane & 15;
  const int g = lane >> 4;
  const int tx = blockIdx.x & 15, ty = (blockIdx.x >> 4) & 15, b = blockIdx.x >> 8;

  // preload 9 tap weight A-fragments (A[row=o][k=c])
  short8 WA[9][2];
#pragma unroll
  for (int kk = 0; kk < 9; ++kk) {
    const short* wb = wcpb + (kk * 16 + olocal) * 64 + g * 8;
    WA[kk][0] = *reinterpret_cast<const short8*>(wb);
    WA[kk][1] = *reinterpret_cast<const short8*>(wb + 32);
  }
  const short* ao = (const short*)aopm;

#pragma unroll
  for (int t = 0; t < 4; ++t) {
    const int oy = wv * 4 + t;      // 0..15
    const int gyc = ty * 16 + oy;
    const int n0 = gyc * WW + tx * 16;
    // seed acc with residual (res16[n][o], lane: px=olocal, o=g*4+r)
    uint2 rv = *reinterpret_cast<const uint2*>(
        &res16[((size_t)b * NPIX + n0 + olocal) * 16 + g * 4]);
    f32x4 acc;
    acc[0] = __uint_as_float(rv.x << 16);
    acc[1] = __uint_as_float(rv.x & 0xffff0000u);
    acc[2] = __uint_as_float(rv.y << 16);
    acc[3] = __uint_as_float(rv.y & 0xffff0000u);
#pragma unroll
    for (int ky = 0; ky < 3; ++ky) {
      const int gy = gyc + ky - 1;
      if ((unsigned)gy < 256u) {
#pragma unroll
        for (int kx = 0; kx < 3; ++kx) {
          const int gx = tx * 16 + kx - 1 + olocal;
          const bool vld = (unsigned)gx < 256u;
          const short* ap = ao + ((size_t)b * NPIX + gy * WW + gx) * 64 + g * 8;
          short8 b0, b1;
          if (vld) {
            b0 = *reinterpret_cast<const short8*>(ap);
            b1 = *reinterpret_cast<const short8*>(ap + 32);
          } else {
            b0 = zero8();
            b1 = zero8();
          }
          acc = __builtin_amdgcn_mfma_f32_16x16x32_bf16(WA[ky * 3 + kx][0], b0, acc, 0, 0, 0);
          acc = __builtin_amdgcn_mfma_f32_16x16x32_bf16(WA[ky * 3 + kx][1], b1, acc, 0, 0, 0);
        }
      }
    }
    float* op = out + ((size_t)b * 16 + g * 4) * NPIX + n0 + olocal;
    op[0] = acc[0];
    op[NPIX] = acc[1];
    op[2 * NPIX] = acc[2];
    op[3 * NPIX] = acc[3];
  }
}

extern "C" void kernel_launch(void* const* d_in, const int* in_sizes, int n_in,
                              void* d_out, int out_size, void* d_ws, size_t ws_size,
                              hipStream_t stream) {
  const float* x      = (const float*)d_in[0];
  const float* ln_w   = (const float*)d_in[1];
  const float* ln_b   = (const float*)d_in[2];
  const float* w_q    = (const float*)d_in[3];
  const float* w_k    = (const float*)d_in[4];
  const float* w_v    = (const float*)d_in[5];
  const float* dw_q   = (const float*)d_in[6];
  const float* dw_k   = (const float*)d_in[7];
  const float* dw_v   = (const float*)d_in[8];
  const float* w_proj = (const float*)d_in[9];
  const float* w_comp = (const float*)d_in[10];
  const float* temp   = (const float*)d_in[11];
  float* out = (float*)d_out;

  const size_t TEN = (size_t)BB * CC * NPIX;  // 33,554,432 elements
  bf16* qb = (bf16*)d_ws;                 // 64 MB; reused as ao (pixel-major)
  bf16* kb = qb + TEN;                    // 64 MB
  bf16* vb = kb + TEN;                    // 64 MB
  short* res16 = (short*)(vb + TEN);      // 8*NPIX*16 shorts = 16 MB
  short* wcpb  = res16 + (size_t)BB * NPIX * 16;  // 9216 shorts
  float* Spart = (float*)(wcpb + 9216);   // 256*256 f32
  float* Qpart = Spart + 65536;           // 4096
  float* Kpart = Qpart + 4096;            // 4096
  float* attn  = Kpart + 4096;            // 8192

  k_wcp<<<36, 256, 0, stream>>>(w_comp, w_proj, wcpb);
  k_lnqkv<<<2048, 512, 0, stream>>>(x, ln_w, ln_b, w_q, w_k, w_v,
                                    dw_q, dw_k, dw_v, w_comp, qb, kb, vb, res16);
  k_logits<<<256, 256, 0, stream>>>(qb, kb, Spart, Qpart, Kpart);
  k_softmax<<<32, 256, 0, stream>>>(Spart, Qpart, Kpart, temp, attn);
  k_attv<<<8192, 256, 0, stream>>>(attn, vb, qb);
  k_final<<<2048, 256, 0, stream>>>(wcpb, qb, res16, out);
}

// Round 5
// 420.204 us; speedup vs baseline: 5.8247x; 1.4781x over previous
//
#include <hip/hip_runtime.h>
#include <hip/hip_bf16.h>
#include <stdint.h>

#define BB 8
#define CC 64
#define HH 256
#define WW 256
#define NPIX 65536
#define HEADS 4
#define HD 16

using bf16 = __hip_bfloat16;
typedef __attribute__((ext_vector_type(8))) short short8;
typedef __attribute__((ext_vector_type(4))) float f32x4;

__device__ __forceinline__ float bf2f(bf16 v) { return __bfloat162float(v); }
__device__ __forceinline__ bf16 f2bf(float v) { return __float2bfloat16(v); }
__device__ __forceinline__ short f2bfs(float f) { bf16 h = __float2bfloat16(f); return *reinterpret_cast<short*>(&h); }
__device__ __forceinline__ float bfs2f(short s) { return __uint_as_float(((uint32_t)(uint16_t)s) << 16); }
__device__ __forceinline__ uint32_t pk2(float a, float b) {
  return (uint32_t)(uint16_t)f2bfs(a) | ((uint32_t)(uint16_t)f2bfs(b) << 16);
}
__device__ __forceinline__ short8 zero8() { short8 z = {0, 0, 0, 0, 0, 0, 0, 0}; return z; }

__device__ __forceinline__ void load8bf(const bf16* p, float* o) {
  uint4 u = *reinterpret_cast<const uint4*>(p);
  o[0] = __uint_as_float(u.x << 16);
  o[1] = __uint_as_float(u.x & 0xffff0000u);
  o[2] = __uint_as_float(u.y << 16);
  o[3] = __uint_as_float(u.y & 0xffff0000u);
  o[4] = __uint_as_float(u.z << 16);
  o[5] = __uint_as_float(u.z & 0xffff0000u);
  o[6] = __uint_as_float(u.w << 16);
  o[7] = __uint_as_float(u.w & 0xffff0000u);
}

// ---------------- kernel: wcpb[kk][o][c] = bf16( sum_m w_comp[o][m] * w_proj[m][c][kk] )
__global__ void k_wcp(const float* __restrict__ w_comp, const float* __restrict__ w_proj,
                      short* __restrict__ wcpb) {
  int idx = blockIdx.x * 256 + threadIdx.x;
  if (idx >= 9 * 16 * 64) return;
  int c = idx & 63;
  int o = (idx >> 6) & 15;
  int kk = idx >> 10;
  float acc = 0.f;
  for (int m = 0; m < 64; ++m)
    acc += w_comp[o * 64 + m] * w_proj[(m * 64 + c) * 9 + kk];
  wcpb[idx] = f2bfs(acc);
}

// ---------------- fused LayerNorm + 1x1 (MFMA) + depthwise 3x3 + residual-compress
__global__ __launch_bounds__(512, 2)
void k_lnqkv(const float* __restrict__ x,
             const float* __restrict__ ln_w, const float* __restrict__ ln_b,
             const float* __restrict__ w_q, const float* __restrict__ w_k,
             const float* __restrict__ w_v,
             const float* __restrict__ dw_q, const float* __restrict__ dw_k,
             const float* __restrict__ dw_v,
             const float* __restrict__ w_comp,
             bf16* __restrict__ qo, bf16* __restrict__ ko, bf16* __restrict__ vo,
             short* __restrict__ res16) {
  __shared__ short xn_s[336 * 72];  // LN'd input, [halo pix][64ch]
  __shared__ short pr_s[336 * 72];  // 1x1 output, [halo pix][64 outch]
  __shared__ short w_s[192 * 72];   // bf16 weights, [t*64+o][64c]
  const int tid = threadIdx.x;
  const int lane = tid & 63;
  const int wv = tid >> 6;          // wave 0..7
  const int olocal = lane & 15;
  const int g = lane >> 4;          // 0..3
  const int tx = blockIdx.x & 15, ty = (blockIdx.x >> 4) & 15, b = blockIdx.x >> 8;

  // stage weights as bf16 into LDS
  {
    const float* Ws[3] = {w_q, w_k, w_v};
    for (int it = tid; it < 1536; it += 512) {
      int row = it >> 3, c8 = it & 7;
      int t = row >> 6, o = row & 63;
      const float* wp = Ws[t] + o * 64 + c8 * 8;
      uint32_t pk[4];
#pragma unroll
      for (int j = 0; j < 4; ++j) pk[j] = pk2(wp[2 * j], wp[2 * j + 1]);
      *reinterpret_cast<uint4*>(&w_s[row * 72 + c8 * 8]) = make_uint4(pk[0], pk[1], pk[2], pk[3]);
    }
  }

  // LayerNorm phase: one thread per halo pixel
  if (tid < 336) {
    const int p = tid;
    bool valid = false;
    int py = 0, px = 0;
    if (p < 324) {
      py = ty * 16 - 1 + p / 18;
      px = tx * 16 - 1 + p % 18;
      valid = (py >= 0 && py < HH && px >= 0 && px < WW);
    }
    if (valid) {
      const float* xp = x + (size_t)b * CC * NPIX + py * WW + px;
      float v[64];
      float s = 0.f, s2 = 0.f;
#pragma unroll
      for (int c = 0; c < 64; ++c) { float t0 = xp[(size_t)c * NPIX]; v[c] = t0; s += t0; s2 += t0 * t0; }
      const float mu = s * (1.f / 64.f);
      const float r = rsqrtf(s2 * (1.f / 64.f) - mu * mu + 1e-6f);
#pragma unroll
      for (int c8 = 0; c8 < 8; ++c8) {
        uint32_t pk[4];
#pragma unroll
        for (int j = 0; j < 4; ++j) {
          const int c0 = c8 * 8 + 2 * j;
          float f0 = (v[c0] - mu) * r * ln_w[c0] + ln_b[c0];
          float f1 = (v[c0 + 1] - mu) * r * ln_w[c0 + 1] + ln_b[c0 + 1];
          pk[j] = pk2(f0, f1);
        }
        *reinterpret_cast<uint4*>(&xn_s[p * 72 + c8 * 8]) = make_uint4(pk[0], pk[1], pk[2], pk[3]);
      }
    } else {
      const uint4 z = make_uint4(0, 0, 0, 0);
#pragma unroll
      for (int c8 = 0; c8 < 8; ++c8)
        *reinterpret_cast<uint4*>(&xn_s[p * 72 + c8 * 8]) = z;
    }
  }
  __syncthreads();

  // residual-compress: res16[b][n][o16] = w_comp @ xn, via MFMA (D rows=o, cols=px)
  {
    short8 wc0, wc1;
    const float* wp = w_comp + olocal * 64 + g * 8;
#pragma unroll
    for (int j = 0; j < 8; ++j) { wc0[j] = f2bfs(wp[j]); wc1[j] = f2bfs(wp[32 + j]); }
#pragma unroll
    for (int t2 = 0; t2 < 2; ++t2) {
      const int oy = wv * 2 + t2;  // 0..15
      const short* bb = &xn_s[((oy + 1) * 18 + 1 + olocal) * 72 + g * 8];
      short8 b0 = *reinterpret_cast<const short8*>(bb);
      short8 b1 = *reinterpret_cast<const short8*>(bb + 32);
      f32x4 acc = {0.f, 0.f, 0.f, 0.f};
      acc = __builtin_amdgcn_mfma_f32_16x16x32_bf16(wc0, b0, acc, 0, 0, 0);
      acc = __builtin_amdgcn_mfma_f32_16x16x32_bf16(wc1, b1, acc, 0, 0, 0);
      const int n = (ty * 16 + oy) * WW + tx * 16 + olocal;
      uint2 st;
      st.x = pk2(acc[0], acc[1]);
      st.y = pk2(acc[2], acc[3]);
      *reinterpret_cast<uint2*>(&res16[((size_t)b * NPIX + n) * 16 + g * 4]) = st;
    }
  }

  for (int t = 0; t < 3; ++t) {
    if (t) __syncthreads();  // pr_s free from previous iteration's phase3
    short8 Bt[4][2];
#pragma unroll
    for (int ot = 0; ot < 4; ++ot) {
      const short* wb = &w_s[(t * 64 + ot * 16 + olocal) * 72 + g * 8];
      Bt[ot][0] = *reinterpret_cast<const short8*>(wb);
      Bt[ot][1] = *reinterpret_cast<const short8*>(wb + 32);
    }
    // phase2: 1x1 projection via MFMA, 21 pixel-tiles of 16
    for (int pt = wv; pt < 21; pt += 8) {
      const short* ab = &xn_s[(pt * 16 + olocal) * 72 + g * 8];
      short8 a0 = *reinterpret_cast<const short8*>(ab);
      short8 a1 = *reinterpret_cast<const short8*>(ab + 32);
#pragma unroll
      for (int ot = 0; ot < 4; ++ot) {
        f32x4 acc = {0.f, 0.f, 0.f, 0.f};
        acc = __builtin_amdgcn_mfma_f32_16x16x32_bf16(a0, Bt[ot][0], acc, 0, 0, 0);
        acc = __builtin_amdgcn_mfma_f32_16x16x32_bf16(a1, Bt[ot][1], acc, 0, 0, 0);
#pragma unroll
        for (int r = 0; r < 4; ++r)
          pr_s[(pt * 16 + g * 4 + r) * 72 + ot * 16 + olocal] = f2bfs(acc[r]);
      }
    }
    __syncthreads();
    // phase3: depthwise 3x3; wave wv owns channels wv*8..wv*8+8
    const float* dmt = (t == 0) ? dw_q : (t == 1) ? dw_k : dw_v;
    bf16* ob = ((t == 0) ? qo : (t == 1) ? ko : vo) + (size_t)b * CC * NPIX;
    float dmr[8][9];
#pragma unroll
    for (int u = 0; u < 8; ++u)
#pragma unroll
      for (int kk = 0; kk < 9; ++kk)
        dmr[u][kk] = dmt[(wv * 8 + u) * 9 + kk];
#pragma unroll
    for (int i = 0; i < 4; ++i) {
      const int pxl = lane + i * 64;
      const int oy = pxl >> 4, ox = pxl & 15;
      float acc8[8] = {0.f, 0.f, 0.f, 0.f, 0.f, 0.f, 0.f, 0.f};
#pragma unroll
      for (int ky = 0; ky < 3; ++ky)
#pragma unroll
        for (int kx = 0; kx < 3; ++kx) {
          const short8 pv = *reinterpret_cast<const short8*>(
              &pr_s[((oy + ky) * 18 + ox + kx) * 72 + wv * 8]);
          const int kk = ky * 3 + kx;
#pragma unroll
          for (int u = 0; u < 8; ++u)
            acc8[u] += dmr[u][kk] * bfs2f(pv[u]);
        }
      const int n = (ty * 16 + oy) * WW + tx * 16 + ox;
#pragma unroll
      for (int u = 0; u < 8; ++u)
        ob[(size_t)(wv * 8 + u) * NPIX + n] = f2bf(acc8[u]);
    }
  }
}

// ---------------- kernel: partial logits + sumsq via MFMA, fragments straight from global
// grid: 32 bh * 64 chunks; block 256 thr = 4 waves; wave owns 256 px (8 K-steps of 32)
__global__ __launch_bounds__(256)
void k_logits(const bf16* __restrict__ q, const bf16* __restrict__ kk_,
              float* __restrict__ Spart, float* __restrict__ Qpart,
              float* __restrict__ Kpart) {
  const int tid = threadIdx.x;
  const int lane = tid & 63;
  const int wv = tid >> 6;            // 0..3
  const int bh = blockIdx.x >> 6;     // 0..31
  const int chunk = blockIdx.x & 63;  // 0..63
  const int row = lane & 15;          // A row / B col / D col
  const int g = lane >> 4;            // 0..3
  const short* qp = (const short*)q + (size_t)(bh * HD + row) * NPIX;
  const short* kp = (const short*)kk_ + (size_t)(bh * HD + row) * NPIX;
  const int n0 = chunk * 1024 + wv * 256 + g * 8;
  f32x4 s = {0.f, 0.f, 0.f, 0.f};
  f32x4 sq = {0.f, 0.f, 0.f, 0.f};
  f32x4 sk = {0.f, 0.f, 0.f, 0.f};
#pragma unroll
  for (int it = 0; it < 8; ++it) {
    const int n = n0 + it * 32;
    short8 qa = *reinterpret_cast<const short8*>(qp + n);
    short8 ka = *reinterpret_cast<const short8*>(kp + n);
    s  = __builtin_amdgcn_mfma_f32_16x16x32_bf16(qa, ka, s, 0, 0, 0);
    sq = __builtin_amdgcn_mfma_f32_16x16x32_bf16(qa, qa, sq, 0, 0, 0);
    sk = __builtin_amdgcn_mfma_f32_16x16x32_bf16(ka, ka, sk, 0, 0, 0);
  }
  // D layout: col = lane&15 (=row var), row i = g*4+r
  const size_t tile = (size_t)blockIdx.x * 4 + wv;
  float* sp = Spart + tile * 256;
#pragma unroll
  for (int r = 0; r < 4; ++r)
    sp[(g * 4 + r) * 16 + row] = s[r];
  if ((row >> 2) == g) {  // diagonal holder lanes
    Qpart[tile * 16 + row] = sq[row & 3];
    Kpart[tile * 16 + row] = sk[row & 3];
  }
}

// ---------------- kernel: reduce partials, normalize, temperature, softmax over j
__global__ __launch_bounds__(256)
void k_softmax(const float* __restrict__ Spart, const float* __restrict__ Qpart,
               const float* __restrict__ Kpart, const float* __restrict__ temp,
               float* __restrict__ attn) {
  const int tid = threadIdx.x;
  const int bh = blockIdx.x;
  const int i = tid >> 4, j = tid & 15;
  float S = 0.f, qs = 0.f, ks = 0.f;
  const size_t t0 = (size_t)bh * 256;  // 64 chunks * 4 waves
  for (int c = 0; c < 256; ++c) {
    S += Spart[(t0 + c) * 256 + tid];
    qs += Qpart[(t0 + c) * 16 + i];
    ks += Kpart[(t0 + c) * 16 + j];
  }
  float nq = fmaxf(sqrtf(qs), 1e-12f);
  float nk = fmaxf(sqrtf(ks), 1e-12f);
  float val = S / (nq * nk) * temp[bh & 3];
  float m = val;
  for (int d = 1; d < 16; d <<= 1) m = fmaxf(m, __shfl_xor(m, d));
  float e = __expf(val - m);
  float s = e;
  for (int d = 1; d < 16; d <<= 1) s += __shfl_xor(s, d);
  attn[bh * 256 + tid] = e / s;
}

// ---------------- kernel: att_out = attn @ v, written PIXEL-MAJOR [b][n][64]
__global__ __launch_bounds__(256)
void k_attv(const float* __restrict__ attn, const bf16* __restrict__ v,
            bf16* __restrict__ aopm) {
  const int tid = threadIdx.x;
  const int bh = blockIdx.x >> 8;
  const int b = bh >> 2, h = bh & 3;
  const int n = ((blockIdx.x & 255) << 8) + tid;
  __shared__ float a_s[256];
  a_s[tid] = attn[bh * 256 + tid];
  __syncthreads();
  const size_t base = (size_t)bh * HD * NPIX;
  float vv[16];
#pragma unroll
  for (int j = 0; j < 16; ++j) vv[j] = bf2f(v[base + (size_t)j * NPIX + n]);
  float o[16];
#pragma unroll
  for (int i = 0; i < 16; ++i) {
    float acc = 0.f;
#pragma unroll
    for (int j = 0; j < 16; ++j) acc += a_s[i * 16 + j] * vv[j];
    o[i] = acc;
  }
  uint4 lo = make_uint4(pk2(o[0], o[1]), pk2(o[2], o[3]), pk2(o[4], o[5]), pk2(o[6], o[7]));
  uint4 hi = make_uint4(pk2(o[8], o[9]), pk2(o[10], o[11]), pk2(o[12], o[13]), pk2(o[14], o[15]));
  short* op = (short*)aopm + ((size_t)b * NPIX + n) * 64 + h * 16;
  *reinterpret_cast<uint4*>(op) = lo;
  *reinterpret_cast<uint4*>(op + 8) = hi;
}

// ---------------- kernel: out = conv3x3(ao, wcp) + res16, pure MFMA, no LDS
__global__ __launch_bounds__(256)
void k_final(const short* __restrict__ wcpb, const bf16* __restrict__ aopm,
             const short* __restrict__ res16, float* __restrict__ out) {
  const int tid = threadIdx.x;
  const int lane = tid & 63;
  const int wv = tid >> 6;          // 0..3
  const int olocal = lane & 15;
  const int g = lane >> 4;
  const int tx = blockIdx.x & 15, ty = (blockIdx.x >> 4) & 15, b = blockIdx.x >> 8;

  // preload 9 tap weight A-fragments (A[row=o][k=c])
  short8 WA[9][2];
#pragma unroll
  for (int kk = 0; kk < 9; ++kk) {
    const short* wb = wcpb + (kk * 16 + olocal) * 64 + g * 8;
    WA[kk][0] = *reinterpret_cast<const short8*>(wb);
    WA[kk][1] = *reinterpret_cast<const short8*>(wb + 32);
  }
  const short* ao = (const short*)aopm;

#pragma unroll
  for (int t = 0; t < 4; ++t) {
    const int oy = wv * 4 + t;      // 0..15
    const int gyc = ty * 16 + oy;
    const int n0 = gyc * WW + tx * 16;
    uint2 rv = *reinterpret_cast<const uint2*>(
        &res16[((size_t)b * NPIX + n0 + olocal) * 16 + g * 4]);
    f32x4 acc;
    acc[0] = __uint_as_float(rv.x << 16);
    acc[1] = __uint_as_float(rv.x & 0xffff0000u);
    acc[2] = __uint_as_float(rv.y << 16);
    acc[3] = __uint_as_float(rv.y & 0xffff0000u);
#pragma unroll
    for (int ky = 0; ky < 3; ++ky) {
      const int gy = gyc + ky - 1;
      if ((unsigned)gy < 256u) {
#pragma unroll
        for (int kx = 0; kx < 3; ++kx) {
          const int gx = tx * 16 + kx - 1 + olocal;
          const bool vld = (unsigned)gx < 256u;
          const short* ap = ao + ((size_t)b * NPIX + gy * WW + gx) * 64 + g * 8;
          short8 b0, b1;
          if (vld) {
            b0 = *reinterpret_cast<const short8*>(ap);
            b1 = *reinterpret_cast<const short8*>(ap + 32);
          } else {
            b0 = zero8();
            b1 = zero8();
          }
          acc = __builtin_amdgcn_mfma_f32_16x16x32_bf16(WA[ky * 3 + kx][0], b0, acc, 0, 0, 0);
          acc = __builtin_amdgcn_mfma_f32_16x16x32_bf16(WA[ky * 3 + kx][1], b1, acc, 0, 0, 0);
        }
      }
    }
    float* op = out + ((size_t)b * 16 + g * 4) * NPIX + n0 + olocal;
    op[0] = acc[0];
    op[NPIX] = acc[1];
    op[2 * NPIX] = acc[2];
    op[3 * NPIX] = acc[3];
  }
}

extern "C" void kernel_launch(void* const* d_in, const int* in_sizes, int n_in,
                              void* d_out, int out_size, void* d_ws, size_t ws_size,
                              hipStream_t stream) {
  const float* x      = (const float*)d_in[0];
  const float* ln_w   = (const float*)d_in[1];
  const float* ln_b   = (const float*)d_in[2];
  const float* w_q    = (const float*)d_in[3];
  const float* w_k    = (const float*)d_in[4];
  const float* w_v    = (const float*)d_in[5];
  const float* dw_q   = (const float*)d_in[6];
  const float* dw_k   = (const float*)d_in[7];
  const float* dw_v   = (const float*)d_in[8];
  const float* w_proj = (const float*)d_in[9];
  const float* w_comp = (const float*)d_in[10];
  const float* temp   = (const float*)d_in[11];
  float* out = (float*)d_out;

  const size_t TEN = (size_t)BB * CC * NPIX;  // 33,554,432 elements
  bf16* qb = (bf16*)d_ws;                 // 64 MB; reused as ao (pixel-major)
  bf16* kb = qb + TEN;                    // 64 MB
  bf16* vb = kb + TEN;                    // 64 MB
  short* res16 = (short*)(vb + TEN);      // 16 MB
  short* wcpb  = res16 + (size_t)BB * NPIX * 16;  // 9216 shorts
  float* Spart = (float*)(wcpb + 9216);   // 32*64*4*256 = 2M f32 (8 MB)
  float* Qpart = Spart + 32 * 256 * 256;  // 32*256*16 = 131072 f32
  float* Kpart = Qpart + 32 * 256 * 16;   // 131072 f32
  float* attn  = Kpart + 32 * 256 * 16;   // 8192

  k_wcp<<<36, 256, 0, stream>>>(w_comp, w_proj, wcpb);
  k_lnqkv<<<2048, 512, 0, stream>>>(x, ln_w, ln_b, w_q, w_k, w_v,
                                    dw_q, dw_k, dw_v, w_comp, qb, kb, vb, res16);
  k_logits<<<2048, 256, 0, stream>>>(qb, kb, Spart, Qpart, Kpart);
  k_softmax<<<32, 256, 0, stream>>>(Spart, Qpart, Kpart, temp, attn);
  k_attv<<<8192, 256, 0, stream>>>(attn, vb, qb);
  k_final<<<2048, 256, 0, stream>>>(wcpb, qb, res16, out);
}

// Round 6
// 410.319 us; speedup vs baseline: 5.9651x; 1.0241x over previous
//
#include <hip/hip_runtime.h>
#include <hip/hip_bf16.h>
#include <stdint.h>

#define BB 8
#define CC 64
#define HH 256
#define WW 256
#define NPIX 65536
#define HEADS 4
#define HD 16
#define PRS 76  // pr_s row stride in shorts (152 B -> 16 distinct banks for b128)

using bf16 = __hip_bfloat16;
typedef __attribute__((ext_vector_type(8))) short short8;
typedef __attribute__((ext_vector_type(4))) float f32x4;

__device__ __forceinline__ float bf2f(bf16 v) { return __bfloat162float(v); }
__device__ __forceinline__ bf16 f2bf(float v) { return __float2bfloat16(v); }
__device__ __forceinline__ short f2bfs(float f) { bf16 h = __float2bfloat16(f); return *reinterpret_cast<short*>(&h); }
__device__ __forceinline__ float bfs2f(short s) { return __uint_as_float(((uint32_t)(uint16_t)s) << 16); }
__device__ __forceinline__ uint32_t pk2(float a, float b) {
  return (uint32_t)(uint16_t)f2bfs(a) | ((uint32_t)(uint16_t)f2bfs(b) << 16);
}
__device__ __forceinline__ short8 zero8() { short8 z = {0, 0, 0, 0, 0, 0, 0, 0}; return z; }

__device__ __forceinline__ void load8bf(const bf16* p, float* o) {
  uint4 u = *reinterpret_cast<const uint4*>(p);
  o[0] = __uint_as_float(u.x << 16);
  o[1] = __uint_as_float(u.x & 0xffff0000u);
  o[2] = __uint_as_float(u.y << 16);
  o[3] = __uint_as_float(u.y & 0xffff0000u);
  o[4] = __uint_as_float(u.z << 16);
  o[5] = __uint_as_float(u.z & 0xffff0000u);
  o[6] = __uint_as_float(u.w << 16);
  o[7] = __uint_as_float(u.w & 0xffff0000u);
}

// ---------------- prep: wcpb = w_comp*w_proj folded (bf16); wqkvb, wcb = bf16 weights
__global__ void k_prep(const float* __restrict__ w_comp, const float* __restrict__ w_proj,
                       const float* __restrict__ w_q, const float* __restrict__ w_k,
                       const float* __restrict__ w_v,
                       short* __restrict__ wcpb, short* __restrict__ wqkvb,
                       short* __restrict__ wcb) {
  int idx = blockIdx.x * 256 + threadIdx.x;
  if (idx < 9 * 16 * 64) {
    int c = idx & 63;
    int o = (idx >> 6) & 15;
    int kk = idx >> 10;
    float acc = 0.f;
    for (int m = 0; m < 64; ++m)
      acc += w_comp[o * 64 + m] * w_proj[(m * 64 + c) * 9 + kk];
    wcpb[idx] = f2bfs(acc);
  }
  if (idx < 3 * 4096) {
    const float* Ws[3] = {w_q, w_k, w_v};
    wqkvb[idx] = f2bfs(Ws[idx >> 12][idx & 4095]);
  }
  if (idx < 1024) wcb[idx] = f2bfs(w_comp[idx]);
}

// ---------------- LayerNorm: x (channel-major fp32) -> xn (pixel-major bf16)
__global__ __launch_bounds__(256)
void k_ln(const float* __restrict__ x, const float* __restrict__ ln_w,
          const float* __restrict__ ln_b, short* __restrict__ xnb) {
  const int tid = threadIdx.x;
  const int b = blockIdx.x >> 8;
  const int n = ((blockIdx.x & 255) << 8) + tid;
  const float* xp = x + (size_t)b * CC * NPIX + n;
  float v[64];
  float s = 0.f, s2 = 0.f;
#pragma unroll
  for (int c = 0; c < 64; ++c) {
    float t0 = xp[(size_t)c * NPIX];
    v[c] = t0; s += t0; s2 += t0 * t0;
  }
  const float mu = s * (1.f / 64.f);
  const float r = rsqrtf(s2 * (1.f / 64.f) - mu * mu + 1e-6f);
  short* op = xnb + ((size_t)b * NPIX + n) * 64;
#pragma unroll
  for (int c8 = 0; c8 < 8; ++c8) {
    uint32_t pk[4];
#pragma unroll
    for (int j = 0; j < 4; ++j) {
      const int c0 = c8 * 8 + 2 * j;
      float f0 = (v[c0] - mu) * r * ln_w[c0] + ln_b[c0];
      float f1 = (v[c0 + 1] - mu) * r * ln_w[c0 + 1] + ln_b[c0 + 1];
      pk[j] = pk2(f0, f1);
    }
    *reinterpret_cast<uint4*>(op + c8 * 8) = make_uint4(pk[0], pk[1], pk[2], pk[3]);
  }
}

// ---------------- QKV: 1x1 (MFMA, frags from global xn) + depthwise 3x3 + res16
__global__ __launch_bounds__(512)
void k_qkv(const short* __restrict__ xnb, const short* __restrict__ wqkvb,
           const short* __restrict__ wcb,
           const float* __restrict__ dw_q, const float* __restrict__ dw_k,
           const float* __restrict__ dw_v,
           bf16* __restrict__ qo, bf16* __restrict__ ko,
           short* __restrict__ aov, short* __restrict__ res16) {
  __shared__ short pr_s[336 * PRS];  // 1x1 output tile, [halo pix][64 outch]
  const int tid = threadIdx.x;
  const int lane = tid & 63;
  const int wv = tid >> 6;          // wave 0..7
  const int olocal = lane & 15;
  const int g = lane >> 4;          // 0..3
  const int tx = blockIdx.x & 15, ty = (blockIdx.x >> 4) & 15, b = blockIdx.x >> 8;
  const int x0 = tx * 16 - 1, y0 = ty * 16 - 1;

  // res16[b][n][o16] = w_comp @ xn (center pixels), 2 rows per wave
  {
    short8 wc0 = *reinterpret_cast<const short8*>(wcb + olocal * 64 + g * 8);
    short8 wc1 = *reinterpret_cast<const short8*>(wcb + olocal * 64 + 32 + g * 8);
#pragma unroll
    for (int t2 = 0; t2 < 2; ++t2) {
      const int oy = wv * 2 + t2;  // 0..15
      const int n = (ty * 16 + oy) * WW + tx * 16 + olocal;
      const short* bb = xnb + ((size_t)b * NPIX + n) * 64 + g * 8;
      short8 b0 = *reinterpret_cast<const short8*>(bb);
      short8 b1 = *reinterpret_cast<const short8*>(bb + 32);
      f32x4 acc = {0.f, 0.f, 0.f, 0.f};
      acc = __builtin_amdgcn_mfma_f32_16x16x32_bf16(wc0, b0, acc, 0, 0, 0);
      acc = __builtin_amdgcn_mfma_f32_16x16x32_bf16(wc1, b1, acc, 0, 0, 0);
      uint2 st;
      st.x = pk2(acc[0], acc[1]);
      st.y = pk2(acc[2], acc[3]);
      *reinterpret_cast<uint2*>(&res16[((size_t)b * NPIX + n) * 16 + g * 4]) = st;
    }
  }

  for (int t = 0; t < 3; ++t) {
    if (t) __syncthreads();  // pr_s free from previous phase3
    // B-frags (bf16 weights) straight from global (L2-hot)
    short8 Bt[4][2];
#pragma unroll
    for (int ot = 0; ot < 4; ++ot) {
      const short* wb = wqkvb + t * 4096 + (ot * 16 + olocal) * 64 + g * 8;
      Bt[ot][0] = *reinterpret_cast<const short8*>(wb);
      Bt[ot][1] = *reinterpret_cast<const short8*>(wb + 32);
    }
    // phase2: 1x1 projection via MFMA; A-frags from global pixel-major xn (halo)
    for (int pt = wv; pt < 21; pt += 8) {
      const int p = pt * 16 + olocal;
      const int py = y0 + p / 18;
      const int px = x0 + p % 18;
      const bool vld = (p < 324) && ((unsigned)py < 256u) && ((unsigned)px < 256u);
      short8 a0 = zero8(), a1 = zero8();
      if (vld) {
        const short* ab = xnb + ((size_t)b * NPIX + py * WW + px) * 64 + g * 8;
        a0 = *reinterpret_cast<const short8*>(ab);
        a1 = *reinterpret_cast<const short8*>(ab + 32);
      }
#pragma unroll
      for (int ot = 0; ot < 4; ++ot) {
        f32x4 acc = {0.f, 0.f, 0.f, 0.f};
        acc = __builtin_amdgcn_mfma_f32_16x16x32_bf16(a0, Bt[ot][0], acc, 0, 0, 0);
        acc = __builtin_amdgcn_mfma_f32_16x16x32_bf16(a1, Bt[ot][1], acc, 0, 0, 0);
#pragma unroll
        for (int r = 0; r < 4; ++r)
          pr_s[(pt * 16 + g * 4 + r) * PRS + ot * 16 + olocal] = f2bfs(acc[r]);
      }
    }
    __syncthreads();
    // phase3: depthwise 3x3; wave wv owns channels wv*8..wv*8+8
    const float* dmt = (t == 0) ? dw_q : (t == 1) ? dw_k : dw_v;
    float dmr[8][9];
#pragma unroll
    for (int u = 0; u < 8; ++u)
#pragma unroll
      for (int kk = 0; kk < 9; ++kk)
        dmr[u][kk] = dmt[(wv * 8 + u) * 9 + kk];
    bf16* ob = ((t == 0) ? qo : ko) + (size_t)b * CC * NPIX;
#pragma unroll
    for (int i = 0; i < 4; ++i) {
      const int pxl = lane + i * 64;
      const int oy = pxl >> 4, ox = pxl & 15;
      float acc8[8] = {0.f, 0.f, 0.f, 0.f, 0.f, 0.f, 0.f, 0.f};
#pragma unroll
      for (int ky = 0; ky < 3; ++ky)
#pragma unroll
        for (int kx = 0; kx < 3; ++kx) {
          const short8 pv = *reinterpret_cast<const short8*>(
              &pr_s[((oy + ky) * 18 + ox + kx) * PRS + wv * 8]);
          const int kk = ky * 3 + kx;
#pragma unroll
          for (int u = 0; u < 8; ++u)
            acc8[u] += dmr[u][kk] * bfs2f(pv[u]);
        }
      const int n = (ty * 16 + oy) * WW + tx * 16 + ox;
      if (t < 2) {
#pragma unroll
        for (int u = 0; u < 8; ++u)
          ob[(size_t)(wv * 8 + u) * NPIX + n] = f2bf(acc8[u]);
      } else {
        // v: pixel-major into aov (k_attv updates in place, k_final reads)
        uint4 st = make_uint4(pk2(acc8[0], acc8[1]), pk2(acc8[2], acc8[3]),
                              pk2(acc8[4], acc8[5]), pk2(acc8[6], acc8[7]));
        *reinterpret_cast<uint4*>(&aov[((size_t)b * NPIX + n) * 64 + wv * 8]) = st;
      }
    }
  }
}

// ---------------- partial logits + sumsq via MFMA, fragments straight from global
__global__ __launch_bounds__(256)
void k_logits(const bf16* __restrict__ q, const bf16* __restrict__ kk_,
              float* __restrict__ Spart, float* __restrict__ Qpart,
              float* __restrict__ Kpart) {
  const int tid = threadIdx.x;
  const int lane = tid & 63;
  const int wv = tid >> 6;            // 0..3
  const int bh = blockIdx.x >> 6;     // 0..31
  const int chunk = blockIdx.x & 63;  // 0..63
  const int row = lane & 15;
  const int g = lane >> 4;
  const short* qp = (const short*)q + (size_t)(bh * HD + row) * NPIX;
  const short* kp = (const short*)kk_ + (size_t)(bh * HD + row) * NPIX;
  const int n0 = chunk * 1024 + wv * 256 + g * 8;
  f32x4 s = {0.f, 0.f, 0.f, 0.f};
  f32x4 sq = {0.f, 0.f, 0.f, 0.f};
  f32x4 sk = {0.f, 0.f, 0.f, 0.f};
#pragma unroll
  for (int it = 0; it < 8; ++it) {
    const int n = n0 + it * 32;
    short8 qa = *reinterpret_cast<const short8*>(qp + n);
    short8 ka = *reinterpret_cast<const short8*>(kp + n);
    s  = __builtin_amdgcn_mfma_f32_16x16x32_bf16(qa, ka, s, 0, 0, 0);
    sq = __builtin_amdgcn_mfma_f32_16x16x32_bf16(qa, qa, sq, 0, 0, 0);
    sk = __builtin_amdgcn_mfma_f32_16x16x32_bf16(ka, ka, sk, 0, 0, 0);
  }
  const size_t tile = (size_t)blockIdx.x * 4 + wv;
  float* sp = Spart + tile * 256;
#pragma unroll
  for (int r = 0; r < 4; ++r)
    sp[(g * 4 + r) * 16 + row] = s[r];
  if ((row >> 2) == g) {
    Qpart[tile * 16 + row] = sq[row & 3];
    Kpart[tile * 16 + row] = sk[row & 3];
  }
}

// ---------------- reduce partials, normalize, temperature, softmax over j
__global__ __launch_bounds__(256)
void k_softmax(const float* __restrict__ Spart, const float* __restrict__ Qpart,
               const float* __restrict__ Kpart, const float* __restrict__ temp,
               float* __restrict__ attn) {
  const int tid = threadIdx.x;
  const int bh = blockIdx.x;
  const int i = tid >> 4, j = tid & 15;
  float S = 0.f, qs = 0.f, ks = 0.f;
  const size_t t0 = (size_t)bh * 256;
  for (int c = 0; c < 256; ++c) {
    S += Spart[(t0 + c) * 256 + tid];
    qs += Qpart[(t0 + c) * 16 + i];
    ks += Kpart[(t0 + c) * 16 + j];
  }
  float nq = fmaxf(sqrtf(qs), 1e-12f);
  float nk = fmaxf(sqrtf(ks), 1e-12f);
  float val = S / (nq * nk) * temp[bh & 3];
  float m = val;
  for (int d = 1; d < 16; d <<= 1) m = fmaxf(m, __shfl_xor(m, d));
  float e = __expf(val - m);
  float s = e;
  for (int d = 1; d < 16; d <<= 1) s += __shfl_xor(s, d);
  attn[bh * 256 + tid] = e / s;
}

// ---------------- att_out = attn @ v, in place on pixel-major aov
__global__ __launch_bounds__(256)
void k_attv(const float* __restrict__ attn, short* __restrict__ aov) {
  const int tid = threadIdx.x;
  const int bh = blockIdx.x >> 8;
  const int b = bh >> 2, h = bh & 3;
  const int n = ((blockIdx.x & 255) << 8) + tid;
  __shared__ float a_s[256];
  a_s[tid] = attn[bh * 256 + tid];
  __syncthreads();
  short* vp = aov + ((size_t)b * NPIX + n) * 64 + h * 16;
  float vv[16];
  load8bf((const bf16*)vp, vv);
  load8bf((const bf16*)(vp + 8), vv + 8);
  float o[16];
#pragma unroll
  for (int i = 0; i < 16; ++i) {
    float acc = 0.f;
#pragma unroll
    for (int j = 0; j < 16; ++j) acc += a_s[i * 16 + j] * vv[j];
    o[i] = acc;
  }
  uint4 lo = make_uint4(pk2(o[0], o[1]), pk2(o[2], o[3]), pk2(o[4], o[5]), pk2(o[6], o[7]));
  uint4 hi = make_uint4(pk2(o[8], o[9]), pk2(o[10], o[11]), pk2(o[12], o[13]), pk2(o[14], o[15]));
  *reinterpret_cast<uint4*>(vp) = lo;
  *reinterpret_cast<uint4*>(vp + 8) = hi;
}

// ---------------- out = conv3x3(ao, wcp) + res16, pure MFMA, no LDS
__global__ __launch_bounds__(256)
void k_final(const short* __restrict__ wcpb, const short* __restrict__ ao,
             const short* __restrict__ res16, float* __restrict__ out) {
  const int tid = threadIdx.x;
  const int lane = tid & 63;
  const int wv = tid >> 6;          // 0..3
  const int olocal = lane & 15;
  const int g = lane >> 4;
  const int tx = blockIdx.x & 15, ty = (blockIdx.x >> 4) & 15, b = blockIdx.x >> 8;

  short8 WA[9][2];
#pragma unroll
  for (int kk = 0; kk < 9; ++kk) {
    const short* wb = wcpb + (kk * 16 + olocal) * 64 + g * 8;
    WA[kk][0] = *reinterpret_cast<const short8*>(wb);
    WA[kk][1] = *reinterpret_cast<const short8*>(wb + 32);
  }

#pragma unroll
  for (int t = 0; t < 4; ++t) {
    const int oy = wv * 4 + t;      // 0..15
    const int gyc = ty * 16 + oy;
    const int n0 = gyc * WW + tx * 16;
    uint2 rv = *reinterpret_cast<const uint2*>(
        &res16[((size_t)b * NPIX + n0 + olocal) * 16 + g * 4]);
    f32x4 acc;
    acc[0] = __uint_as_float(rv.x << 16);
    acc[1] = __uint_as_float(rv.x & 0xffff0000u);
    acc[2] = __uint_as_float(rv.y << 16);
    acc[3] = __uint_as_float(rv.y & 0xffff0000u);
#pragma unroll
    for (int ky = 0; ky < 3; ++ky) {
      const int gy = gyc + ky - 1;
      if ((unsigned)gy < 256u) {
#pragma unroll
        for (int kx = 0; kx < 3; ++kx) {
          const int gx = tx * 16 + kx - 1 + olocal;
          const bool vld = (unsigned)gx < 256u;
          const short* ap = ao + ((size_t)b * NPIX + gy * WW + gx) * 64 + g * 8;
          short8 b0, b1;
          if (vld) {
            b0 = *reinterpret_cast<const short8*>(ap);
            b1 = *reinterpret_cast<const short8*>(ap + 32);
          } else {
            b0 = zero8();
            b1 = zero8();
          }
          acc = __builtin_amdgcn_mfma_f32_16x16x32_bf16(WA[ky * 3 + kx][0], b0, acc, 0, 0, 0);
          acc = __builtin_amdgcn_mfma_f32_16x16x32_bf16(WA[ky * 3 + kx][1], b1, acc, 0, 0, 0);
        }
      }
    }
    float* op = out + ((size_t)b * 16 + g * 4) * NPIX + n0 + olocal;
    op[0] = acc[0];
    op[NPIX] = acc[1];
    op[2 * NPIX] = acc[2];
    op[3 * NPIX] = acc[3];
  }
}

extern "C" void kernel_launch(void* const* d_in, const int* in_sizes, int n_in,
                              void* d_out, int out_size, void* d_ws, size_t ws_size,
                              hipStream_t stream) {
  const float* x      = (const float*)d_in[0];
  const float* ln_w   = (const float*)d_in[1];
  const float* ln_b   = (const float*)d_in[2];
  const float* w_q    = (const float*)d_in[3];
  const float* w_k    = (const float*)d_in[4];
  const float* w_v    = (const float*)d_in[5];
  const float* dw_q   = (const float*)d_in[6];
  const float* dw_k   = (const float*)d_in[7];
  const float* dw_v   = (const float*)d_in[8];
  const float* w_proj = (const float*)d_in[9];
  const float* w_comp = (const float*)d_in[10];
  const float* temp   = (const float*)d_in[11];
  float* out = (float*)d_out;

  const size_t SPX = (size_t)BB * NPIX;   // 524288 pixels
  short* xnb   = (short*)d_ws;            // SPX*64  (67 MB) pixel-major LN'd x
  short* qb    = xnb + SPX * 64;          // planar bf16 q
  short* kb    = qb + SPX * 64;           // planar bf16 k
  short* aov   = kb + SPX * 64;           // pixel-major v, then att_out in place
  short* res16 = aov + SPX * 64;          // SPX*16 (16 MB)
  short* wcpb  = res16 + SPX * 16;        // 9216
  short* wqkvb = wcpb + 9216;             // 12288
  short* wcb   = wqkvb + 12288;           // 1024
  float* Spart = (float*)(wcb + 1024);    // 32*256*256 f32 (8 MB)
  float* Qpart = Spart + 32 * 256 * 256;
  float* Kpart = Qpart + 32 * 256 * 16;
  float* attn  = Kpart + 32 * 256 * 16;

  k_prep<<<52, 256, 0, stream>>>(w_comp, w_proj, w_q, w_k, w_v, wcpb, wqkvb, wcb);
  k_ln<<<2048, 256, 0, stream>>>(x, ln_w, ln_b, xnb);
  k_qkv<<<2048, 512, 0, stream>>>(xnb, wqkvb, wcb, dw_q, dw_k, dw_v,
                                  (bf16*)qb, (bf16*)kb, aov, res16);
  k_logits<<<2048, 256, 0, stream>>>((const bf16*)qb, (const bf16*)kb, Spart, Qpart, Kpart);
  k_softmax<<<32, 256, 0, stream>>>(Spart, Qpart, Kpart, temp, attn);
  k_attv<<<8192, 256, 0, stream>>>(attn, aov);
  k_final<<<2048, 256, 0, stream>>>(wcpb, aov, res16, out);
}

// Round 7
// 382.149 us; speedup vs baseline: 6.4048x; 1.0737x over previous
//
#include <hip/hip_runtime.h>
#include <hip/hip_bf16.h>
#include <stdint.h>

#define BB 8
#define CC 64
#define HH 256
#define WW 256
#define NPIX 65536
#define HEADS 4
#define HD 16
#define PRS 76  // pr_s row stride in shorts (152 B -> conflict-free b128 pattern, verified r6)

using bf16 = __hip_bfloat16;
typedef __attribute__((ext_vector_type(8))) short short8;
typedef __attribute__((ext_vector_type(4))) float f32x4;

__device__ __forceinline__ float bf2f(bf16 v) { return __bfloat162float(v); }
__device__ __forceinline__ bf16 f2bf(float v) { return __float2bfloat16(v); }
__device__ __forceinline__ short f2bfs(float f) { bf16 h = __float2bfloat16(f); return *reinterpret_cast<short*>(&h); }
__device__ __forceinline__ float bfs2f(short s) { return __uint_as_float(((uint32_t)(uint16_t)s) << 16); }
__device__ __forceinline__ uint32_t pk2(float a, float b) {
  return (uint32_t)(uint16_t)f2bfs(a) | ((uint32_t)(uint16_t)f2bfs(b) << 16);
}
__device__ __forceinline__ short8 zero8() { short8 z = {0, 0, 0, 0, 0, 0, 0, 0}; return z; }

__device__ __forceinline__ void load8bf(const bf16* p, float* o) {
  uint4 u = *reinterpret_cast<const uint4*>(p);
  o[0] = __uint_as_float(u.x << 16);
  o[1] = __uint_as_float(u.x & 0xffff0000u);
  o[2] = __uint_as_float(u.y << 16);
  o[3] = __uint_as_float(u.y & 0xffff0000u);
  o[4] = __uint_as_float(u.z << 16);
  o[5] = __uint_as_float(u.z & 0xffff0000u);
  o[6] = __uint_as_float(u.w << 16);
  o[7] = __uint_as_float(u.w & 0xffff0000u);
}

// ---------------- prep: wcpb = w_comp*w_proj folded (bf16); wqkvb, wcb = bf16 weights
__global__ void k_prep(const float* __restrict__ w_comp, const float* __restrict__ w_proj,
                       const float* __restrict__ w_q, const float* __restrict__ w_k,
                       const float* __restrict__ w_v,
                       short* __restrict__ wcpb, short* __restrict__ wqkvb,
                       short* __restrict__ wcb) {
  int idx = blockIdx.x * 256 + threadIdx.x;
  if (idx < 9 * 16 * 64) {
    int c = idx & 63;
    int o = (idx >> 6) & 15;
    int kk = idx >> 10;
    float acc = 0.f;
    for (int m = 0; m < 64; ++m)
      acc += w_comp[o * 64 + m] * w_proj[(m * 64 + c) * 9 + kk];
    wcpb[idx] = f2bfs(acc);
  }
  if (idx < 3 * 4096) {
    const float* Ws[3] = {w_q, w_k, w_v};
    wqkvb[idx] = f2bfs(Ws[idx >> 12][idx & 4095]);
  }
  if (idx < 1024) wcb[idx] = f2bfs(w_comp[idx]);
}

// ---------------- LayerNorm: x (channel-major fp32) -> xn (pixel-major bf16)
__global__ __launch_bounds__(256)
void k_ln(const float* __restrict__ x, const float* __restrict__ ln_w,
          const float* __restrict__ ln_b, short* __restrict__ xnb) {
  const int tid = threadIdx.x;
  const int b = blockIdx.x >> 8;
  const int n = ((blockIdx.x & 255) << 8) + tid;
  const float* xp = x + (size_t)b * CC * NPIX + n;
  float v[64];
  float s = 0.f, s2 = 0.f;
#pragma unroll
  for (int c = 0; c < 64; ++c) {
    float t0 = xp[(size_t)c * NPIX];
    v[c] = t0; s += t0; s2 += t0 * t0;
  }
  const float mu = s * (1.f / 64.f);
  const float r = rsqrtf(s2 * (1.f / 64.f) - mu * mu + 1e-6f);
  short* op = xnb + ((size_t)b * NPIX + n) * 64;
#pragma unroll
  for (int c8 = 0; c8 < 8; ++c8) {
    uint32_t pk[4];
#pragma unroll
    for (int j = 0; j < 4; ++j) {
      const int c0 = c8 * 8 + 2 * j;
      float f0 = (v[c0] - mu) * r * ln_w[c0] + ln_b[c0];
      float f1 = (v[c0 + 1] - mu) * r * ln_w[c0 + 1] + ln_b[c0 + 1];
      pk[j] = pk2(f0, f1);
    }
    *reinterpret_cast<uint4*>(op + c8 * 8) = make_uint4(pk[0], pk[1], pk[2], pk[3]);
  }
}

// ---------------- QKV (t = blockIdx.y): 1x1 MFMA + depthwise 3x3; one barrier
__global__ __launch_bounds__(512)
void k_qkv(const short* __restrict__ xnb, const short* __restrict__ wqkvb,
           const short* __restrict__ wcb,
           const float* __restrict__ dw_q, const float* __restrict__ dw_k,
           const float* __restrict__ dw_v,
           bf16* __restrict__ qo, bf16* __restrict__ ko,
           short* __restrict__ aov, short* __restrict__ res16) {
  __shared__ short pr_s[336 * PRS];  // 1x1 output tile, [halo pix][64 outch]
  const int tid = threadIdx.x;
  const int lane = tid & 63;
  const int wv = tid >> 6;          // wave 0..7
  const int olocal = lane & 15;
  const int g = lane >> 4;          // 0..3
  const int t = blockIdx.y;         // 0=q, 1=k, 2=v
  const int tx = blockIdx.x & 15, ty = (blockIdx.x >> 4) & 15, b = blockIdx.x >> 8;
  const int x0 = tx * 16 - 1, y0 = ty * 16 - 1;

  // res16[b][n][o16] = w_comp @ xn (center pixels) — only in the t==0 slice
  if (t == 0) {
    short8 wc0 = *reinterpret_cast<const short8*>(wcb + olocal * 64 + g * 8);
    short8 wc1 = *reinterpret_cast<const short8*>(wcb + olocal * 64 + 32 + g * 8);
#pragma unroll
    for (int t2 = 0; t2 < 2; ++t2) {
      const int oy = wv * 2 + t2;  // 0..15
      const int n = (ty * 16 + oy) * WW + tx * 16 + olocal;
      const short* bb = xnb + ((size_t)b * NPIX + n) * 64 + g * 8;
      short8 b0 = *reinterpret_cast<const short8*>(bb);
      short8 b1 = *reinterpret_cast<const short8*>(bb + 32);
      f32x4 acc = {0.f, 0.f, 0.f, 0.f};
      acc = __builtin_amdgcn_mfma_f32_16x16x32_bf16(wc0, b0, acc, 0, 0, 0);
      acc = __builtin_amdgcn_mfma_f32_16x16x32_bf16(wc1, b1, acc, 0, 0, 0);
      uint2 st;
      st.x = pk2(acc[0], acc[1]);
      st.y = pk2(acc[2], acc[3]);
      *reinterpret_cast<uint2*>(&res16[((size_t)b * NPIX + n) * 16 + g * 4]) = st;
    }
  }

  // B-frags (bf16 weights) straight from global (L2-hot)
  short8 Bt[4][2];
#pragma unroll
  for (int ot = 0; ot < 4; ++ot) {
    const short* wb = wqkvb + t * 4096 + (ot * 16 + olocal) * 64 + g * 8;
    Bt[ot][0] = *reinterpret_cast<const short8*>(wb);
    Bt[ot][1] = *reinterpret_cast<const short8*>(wb + 32);
  }

  // phase2: 1x1 projection via MFMA. Hoist all 3 A-frag pairs, then MFMA cluster.
  short8 a0[3], a1[3];
#pragma unroll
  for (int j = 0; j < 3; ++j) {
    const int pt = wv + j * 8;
    const int p = pt * 16 + olocal;
    const int py = y0 + p / 18;
    const int px_ = x0 + p % 18;
    const bool vld = (pt < 21) && (p < 324) && ((unsigned)py < 256u) && ((unsigned)px_ < 256u);
    if (vld) {
      const short* ab = xnb + ((size_t)b * NPIX + py * WW + px_) * 64 + g * 8;
      a0[j] = *reinterpret_cast<const short8*>(ab);
      a1[j] = *reinterpret_cast<const short8*>(ab + 32);
    } else {
      a0[j] = zero8();
      a1[j] = zero8();
    }
  }
#pragma unroll
  for (int j = 0; j < 3; ++j) {
    const int pt = wv + j * 8;
    if (pt >= 21) continue;
#pragma unroll
    for (int ot = 0; ot < 4; ++ot) {
      f32x4 acc = {0.f, 0.f, 0.f, 0.f};
      acc = __builtin_amdgcn_mfma_f32_16x16x32_bf16(a0[j], Bt[ot][0], acc, 0, 0, 0);
      acc = __builtin_amdgcn_mfma_f32_16x16x32_bf16(a1[j], Bt[ot][1], acc, 0, 0, 0);
#pragma unroll
      for (int r = 0; r < 4; ++r)
        pr_s[(pt * 16 + g * 4 + r) * PRS + ot * 16 + olocal] = f2bfs(acc[r]);
    }
  }
  __syncthreads();

  // phase3: depthwise 3x3; wave wv owns channels wv*8..wv*8+8
  const float* dmt = (t == 0) ? dw_q : (t == 1) ? dw_k : dw_v;
  float dmr[8][9];
#pragma unroll
  for (int u = 0; u < 8; ++u)
#pragma unroll
    for (int kk = 0; kk < 9; ++kk)
      dmr[u][kk] = dmt[(wv * 8 + u) * 9 + kk];
  bf16* ob = ((t == 0) ? qo : ko) + (size_t)b * CC * NPIX;
#pragma unroll
  for (int i = 0; i < 4; ++i) {
    const int pxl = lane + i * 64;
    const int oy = pxl >> 4, ox = pxl & 15;
    float acc8[8] = {0.f, 0.f, 0.f, 0.f, 0.f, 0.f, 0.f, 0.f};
#pragma unroll
    for (int ky = 0; ky < 3; ++ky)
#pragma unroll
      for (int kx = 0; kx < 3; ++kx) {
        const short8 pv = *reinterpret_cast<const short8*>(
            &pr_s[((oy + ky) * 18 + ox + kx) * PRS + wv * 8]);
        const int kk = ky * 3 + kx;
#pragma unroll
        for (int u = 0; u < 8; ++u)
          acc8[u] += dmr[u][kk] * bfs2f(pv[u]);
      }
    const int n = (ty * 16 + oy) * WW + tx * 16 + ox;
    if (t < 2) {
#pragma unroll
      for (int u = 0; u < 8; ++u)
        ob[(size_t)(wv * 8 + u) * NPIX + n] = f2bf(acc8[u]);
    } else {
      uint4 st = make_uint4(pk2(acc8[0], acc8[1]), pk2(acc8[2], acc8[3]),
                            pk2(acc8[4], acc8[5]), pk2(acc8[6], acc8[7]));
      *reinterpret_cast<uint4*>(&aov[((size_t)b * NPIX + n) * 64 + wv * 8]) = st;
    }
  }
}

// ---------------- partial logits + sumsq via MFMA, fragments straight from global
__global__ __launch_bounds__(256)
void k_logits(const bf16* __restrict__ q, const bf16* __restrict__ kk_,
              float* __restrict__ Spart, float* __restrict__ Qpart,
              float* __restrict__ Kpart) {
  const int tid = threadIdx.x;
  const int lane = tid & 63;
  const int wv = tid >> 6;            // 0..3
  const int bh = blockIdx.x >> 6;     // 0..31
  const int chunk = blockIdx.x & 63;  // 0..63
  const int row = lane & 15;
  const int g = lane >> 4;
  const short* qp = (const short*)q + (size_t)(bh * HD + row) * NPIX;
  const short* kp = (const short*)kk_ + (size_t)(bh * HD + row) * NPIX;
  const int n0 = chunk * 1024 + wv * 256 + g * 8;
  f32x4 s = {0.f, 0.f, 0.f, 0.f};
  f32x4 sq = {0.f, 0.f, 0.f, 0.f};
  f32x4 sk = {0.f, 0.f, 0.f, 0.f};
#pragma unroll
  for (int it = 0; it < 8; ++it) {
    const int n = n0 + it * 32;
    short8 qa = *reinterpret_cast<const short8*>(qp + n);
    short8 ka = *reinterpret_cast<const short8*>(kp + n);
    s  = __builtin_amdgcn_mfma_f32_16x16x32_bf16(qa, ka, s, 0, 0, 0);
    sq = __builtin_amdgcn_mfma_f32_16x16x32_bf16(qa, qa, sq, 0, 0, 0);
    sk = __builtin_amdgcn_mfma_f32_16x16x32_bf16(ka, ka, sk, 0, 0, 0);
  }
  const size_t tile = (size_t)blockIdx.x * 4 + wv;
  float* sp = Spart + tile * 256;
#pragma unroll
  for (int r = 0; r < 4; ++r)
    sp[(g * 4 + r) * 16 + row] = s[r];
  if ((row >> 2) == g) {
    Qpart[tile * 16 + row] = sq[row & 3];
    Kpart[tile * 16 + row] = sk[row & 3];
  }
}

// ---------------- reduce partials, normalize, temperature, softmax over j
__global__ __launch_bounds__(256)
void k_softmax(const float* __restrict__ Spart, const float* __restrict__ Qpart,
               const float* __restrict__ Kpart, const float* __restrict__ temp,
               float* __restrict__ attn) {
  const int tid = threadIdx.x;
  const int bh = blockIdx.x;
  const int i = tid >> 4, j = tid & 15;
  float S = 0.f, qs = 0.f, ks = 0.f;
  const size_t t0 = (size_t)bh * 256;
  for (int c = 0; c < 256; ++c) {
    S += Spart[(t0 + c) * 256 + tid];
    qs += Qpart[(t0 + c) * 16 + i];
    ks += Kpart[(t0 + c) * 16 + j];
  }
  float nq = fmaxf(sqrtf(qs), 1e-12f);
  float nk = fmaxf(sqrtf(ks), 1e-12f);
  float val = S / (nq * nk) * temp[bh & 3];
  float m = val;
  for (int d = 1; d < 16; d <<= 1) m = fmaxf(m, __shfl_xor(m, d));
  float e = __expf(val - m);
  float s = e;
  for (int d = 1; d < 16; d <<= 1) s += __shfl_xor(s, d);
  attn[bh * 256 + tid] = e / s;
}

// ---------------- att_out = attn @ v, in place on pixel-major aov
__global__ __launch_bounds__(256)
void k_attv(const float* __restrict__ attn, short* __restrict__ aov) {
  const int tid = threadIdx.x;
  const int bh = blockIdx.x >> 8;
  const int b = bh >> 2, h = bh & 3;
  const int n = ((blockIdx.x & 255) << 8) + tid;
  __shared__ float a_s[256];
  a_s[tid] = attn[bh * 256 + tid];
  __syncthreads();
  short* vp = aov + ((size_t)b * NPIX + n) * 64 + h * 16;
  float vv[16];
  load8bf((const bf16*)vp, vv);
  load8bf((const bf16*)(vp + 8), vv + 8);
  float o[16];
#pragma unroll
  for (int i = 0; i < 16; ++i) {
    float acc = 0.f;
#pragma unroll
    for (int j = 0; j < 16; ++j) acc += a_s[i * 16 + j] * vv[j];
    o[i] = acc;
  }
  uint4 lo = make_uint4(pk2(o[0], o[1]), pk2(o[2], o[3]), pk2(o[4], o[5]), pk2(o[6], o[7]));
  uint4 hi = make_uint4(pk2(o[8], o[9]), pk2(o[10], o[11]), pk2(o[12], o[13]), pk2(o[14], o[15]));
  *reinterpret_cast<uint4*>(vp) = lo;
  *reinterpret_cast<uint4*>(vp + 8) = hi;
}

// ---------------- out = conv3x3(ao, wcp) + res16, pure MFMA, no LDS
__global__ __launch_bounds__(256)
void k_final(const short* __restrict__ wcpb, const short* __restrict__ ao,
             const short* __restrict__ res16, float* __restrict__ out) {
  const int tid = threadIdx.x;
  const int lane = tid & 63;
  const int wv = tid >> 6;          // 0..3
  const int olocal = lane & 15;
  const int g = lane >> 4;
  const int tx = blockIdx.x & 15, ty = (blockIdx.x >> 4) & 15, b = blockIdx.x >> 8;

  short8 WA[9][2];
#pragma unroll
  for (int kk = 0; kk < 9; ++kk) {
    const short* wb = wcpb + (kk * 16 + olocal) * 64 + g * 8;
    WA[kk][0] = *reinterpret_cast<const short8*>(wb);
    WA[kk][1] = *reinterpret_cast<const short8*>(wb + 32);
  }

#pragma unroll
  for (int t = 0; t < 4; ++t) {
    const int oy = wv * 4 + t;      // 0..15
    const int gyc = ty * 16 + oy;
    const int n0 = gyc * WW + tx * 16;
    uint2 rv = *reinterpret_cast<const uint2*>(
        &res16[((size_t)b * NPIX + n0 + olocal) * 16 + g * 4]);
    f32x4 acc;
    acc[0] = __uint_as_float(rv.x << 16);
    acc[1] = __uint_as_float(rv.x & 0xffff0000u);
    acc[2] = __uint_as_float(rv.y << 16);
    acc[3] = __uint_as_float(rv.y & 0xffff0000u);
#pragma unroll
    for (int ky = 0; ky < 3; ++ky) {
      const int gy = gyc + ky - 1;
      if ((unsigned)gy < 256u) {
#pragma unroll
        for (int kx = 0; kx < 3; ++kx) {
          const int gx = tx * 16 + kx - 1 + olocal;
          const bool vld = (unsigned)gx < 256u;
          const short* ap = ao + ((size_t)b * NPIX + gy * WW + gx) * 64 + g * 8;
          short8 b0, b1;
          if (vld) {
            b0 = *reinterpret_cast<const short8*>(ap);
            b1 = *reinterpret_cast<const short8*>(ap + 32);
          } else {
            b0 = zero8();
            b1 = zero8();
          }
          acc = __builtin_amdgcn_mfma_f32_16x16x32_bf16(WA[ky * 3 + kx][0], b0, acc, 0, 0, 0);
          acc = __builtin_amdgcn_mfma_f32_16x16x32_bf16(WA[ky * 3 + kx][1], b1, acc, 0, 0, 0);
        }
      }
    }
    float* op = out + ((size_t)b * 16 + g * 4) * NPIX + n0 + olocal;
    op[0] = acc[0];
    op[NPIX] = acc[1];
    op[2 * NPIX] = acc[2];
    op[3 * NPIX] = acc[3];
  }
}

extern "C" void kernel_launch(void* const* d_in, const int* in_sizes, int n_in,
                              void* d_out, int out_size, void* d_ws, size_t ws_size,
                              hipStream_t stream) {
  const float* x      = (const float*)d_in[0];
  const float* ln_w   = (const float*)d_in[1];
  const float* ln_b   = (const float*)d_in[2];
  const float* w_q    = (const float*)d_in[3];
  const float* w_k    = (const float*)d_in[4];
  const float* w_v    = (const float*)d_in[5];
  const float* dw_q   = (const float*)d_in[6];
  const float* dw_k   = (const float*)d_in[7];
  const float* dw_v   = (const float*)d_in[8];
  const float* w_proj = (const float*)d_in[9];
  const float* w_comp = (const float*)d_in[10];
  const float* temp   = (const float*)d_in[11];
  float* out = (float*)d_out;

  const size_t SPX = (size_t)BB * NPIX;   // 524288 pixels
  short* xnb   = (short*)d_ws;            // SPX*64  (67 MB) pixel-major LN'd x
  short* qb    = xnb + SPX * 64;          // planar bf16 q
  short* kb    = qb + SPX * 64;           // planar bf16 k
  short* aov   = kb + SPX * 64;           // pixel-major v, then att_out in place
  short* res16 = aov + SPX * 64;          // SPX*16 (16 MB)
  short* wcpb  = res16 + SPX * 16;        // 9216
  short* wqkvb = wcpb + 9216;             // 12288
  short* wcb   = wqkvb + 12288;           // 1024
  float* Spart = (float*)(wcb + 1024);    // 32*256*256 f32 (8 MB)
  float* Qpart = Spart + 32 * 256 * 256;
  float* Kpart = Qpart + 32 * 256 * 16;
  float* attn  = Kpart + 32 * 256 * 16;

  k_prep<<<52, 256, 0, stream>>>(w_comp, w_proj, w_q, w_k, w_v, wcpb, wqkvb, wcb);
  k_ln<<<2048, 256, 0, stream>>>(x, ln_w, ln_b, xnb);
  dim3 gqkv(2048, 3);
  k_qkv<<<gqkv, 512, 0, stream>>>(xnb, wqkvb, wcb, dw_q, dw_k, dw_v,
                                  (bf16*)qb, (bf16*)kb, aov, res16);
  k_logits<<<2048, 256, 0, stream>>>((const bf16*)qb, (const bf16*)kb, Spart, Qpart, Kpart);
  k_softmax<<<32, 256, 0, stream>>>(Spart, Qpart, Kpart, temp, attn);
  k_attv<<<8192, 256, 0, stream>>>(attn, aov);
  k_final<<<2048, 256, 0, stream>>>(wcpb, aov, res16, out);
}

// Round 8
// 320.617 us; speedup vs baseline: 7.6340x; 1.1919x over previous
//
#include <hip/hip_runtime.h>
#include <hip/hip_bf16.h>
#include <stdint.h>

#define BB 8
#define CC 64
#define HH 256
#define WW 256
#define NPIX 65536
#define HEADS 4
#define HD 16
#define PRS 76  // LDS row stride in shorts (152 B -> conflict-free b128 reads, verified r6)

using bf16 = __hip_bfloat16;
typedef __attribute__((ext_vector_type(8))) short short8;
typedef __attribute__((ext_vector_type(4))) float f32x4;

__device__ __forceinline__ float bf2f(bf16 v) { return __bfloat162float(v); }
__device__ __forceinline__ bf16 f2bf(float v) { return __float2bfloat16(v); }
__device__ __forceinline__ short f2bfs(float f) { bf16 h = __float2bfloat16(f); return *reinterpret_cast<short*>(&h); }
__device__ __forceinline__ float bfs2f(short s) { return __uint_as_float(((uint32_t)(uint16_t)s) << 16); }
__device__ __forceinline__ uint32_t pk2(float a, float b) {
  return (uint32_t)(uint16_t)f2bfs(a) | ((uint32_t)(uint16_t)f2bfs(b) << 16);
}
__device__ __forceinline__ short8 zero8() { short8 z = {0, 0, 0, 0, 0, 0, 0, 0}; return z; }

// ---------------- prep: wcpb = w_comp*w_proj folded (bf16); wqkvb, wcb = bf16 weights
__global__ void k_prep(const float* __restrict__ w_comp, const float* __restrict__ w_proj,
                       const float* __restrict__ w_q, const float* __restrict__ w_k,
                       const float* __restrict__ w_v,
                       short* __restrict__ wcpb, short* __restrict__ wqkvb,
                       short* __restrict__ wcb) {
  int idx = blockIdx.x * 256 + threadIdx.x;
  if (idx < 9 * 16 * 64) {
    int c = idx & 63;
    int o = (idx >> 6) & 15;
    int kk = idx >> 10;
    float acc = 0.f;
    for (int m = 0; m < 64; ++m)
      acc += w_comp[o * 64 + m] * w_proj[(m * 64 + c) * 9 + kk];
    wcpb[idx] = f2bfs(acc);
  }
  if (idx < 3 * 4096) {
    const float* Ws[3] = {w_q, w_k, w_v};
    wqkvb[idx] = f2bfs(Ws[idx >> 12][idx & 4095]);
  }
  if (idx < 1024) wcb[idx] = f2bfs(w_comp[idx]);
}

// ---------------- LayerNorm: x (channel-major fp32) -> xn (pixel-major bf16)
__global__ __launch_bounds__(256)
void k_ln(const float* __restrict__ x, const float* __restrict__ ln_w,
          const float* __restrict__ ln_b, short* __restrict__ xnb) {
  const int tid = threadIdx.x;
  const int b = blockIdx.x >> 8;
  const int n = ((blockIdx.x & 255) << 8) + tid;
  const float* xp = x + (size_t)b * CC * NPIX + n;
  float v[64];
  float s = 0.f, s2 = 0.f;
#pragma unroll
  for (int c = 0; c < 64; ++c) {
    float t0 = xp[(size_t)c * NPIX];
    v[c] = t0; s += t0; s2 += t0 * t0;
  }
  const float mu = s * (1.f / 64.f);
  const float r = rsqrtf(s2 * (1.f / 64.f) - mu * mu + 1e-6f);
  short* op = xnb + ((size_t)b * NPIX + n) * 64;
#pragma unroll
  for (int c8 = 0; c8 < 8; ++c8) {
    uint32_t pk[4];
#pragma unroll
    for (int j = 0; j < 4; ++j) {
      const int c0 = c8 * 8 + 2 * j;
      float f0 = (v[c0] - mu) * r * ln_w[c0] + ln_b[c0];
      float f1 = (v[c0 + 1] - mu) * r * ln_w[c0 + 1] + ln_b[c0 + 1];
      pk[j] = pk2(f0, f1);
    }
    *reinterpret_cast<uint4*>(op + c8 * 8) = make_uint4(pk[0], pk[1], pk[2], pk[3]);
  }
}

// ---------------- QKV (t = blockIdx.y): 1x1 MFMA + depthwise 3x3; one barrier
__global__ __launch_bounds__(512)
void k_qkv(const short* __restrict__ xnb, const short* __restrict__ wqkvb,
           const short* __restrict__ wcb,
           const float* __restrict__ dw_q, const float* __restrict__ dw_k,
           const float* __restrict__ dw_v,
           bf16* __restrict__ qo, bf16* __restrict__ ko,
           short* __restrict__ aov, short* __restrict__ res16) {
  __shared__ short pr_s[336 * PRS];  // 1x1 output tile, [halo pix][64 outch]
  const int tid = threadIdx.x;
  const int lane = tid & 63;
  const int wv = tid >> 6;          // wave 0..7
  const int olocal = lane & 15;
  const int g = lane >> 4;          // 0..3
  const int t = blockIdx.y;         // 0=q, 1=k, 2=v
  const int tx = blockIdx.x & 15, ty = (blockIdx.x >> 4) & 15, b = blockIdx.x >> 8;
  const int x0 = tx * 16 - 1, y0 = ty * 16 - 1;

  // res16[b][n][o16] = w_comp @ xn (center pixels) — only in the t==0 slice
  if (t == 0) {
    short8 wc0 = *reinterpret_cast<const short8*>(wcb + olocal * 64 + g * 8);
    short8 wc1 = *reinterpret_cast<const short8*>(wcb + olocal * 64 + 32 + g * 8);
#pragma unroll
    for (int t2 = 0; t2 < 2; ++t2) {
      const int oy = wv * 2 + t2;  // 0..15
      const int n = (ty * 16 + oy) * WW + tx * 16 + olocal;
      const short* bb = xnb + ((size_t)b * NPIX + n) * 64 + g * 8;
      short8 b0 = *reinterpret_cast<const short8*>(bb);
      short8 b1 = *reinterpret_cast<const short8*>(bb + 32);
      f32x4 acc = {0.f, 0.f, 0.f, 0.f};
      acc = __builtin_amdgcn_mfma_f32_16x16x32_bf16(wc0, b0, acc, 0, 0, 0);
      acc = __builtin_amdgcn_mfma_f32_16x16x32_bf16(wc1, b1, acc, 0, 0, 0);
      uint2 st;
      st.x = pk2(acc[0], acc[1]);
      st.y = pk2(acc[2], acc[3]);
      *reinterpret_cast<uint2*>(&res16[((size_t)b * NPIX + n) * 16 + g * 4]) = st;
    }
  }

  // A-frags (bf16 weights) straight from global (L2-hot)
  short8 Bt[4][2];
#pragma unroll
  for (int ot = 0; ot < 4; ++ot) {
    const short* wb = wqkvb + t * 4096 + (ot * 16 + olocal) * 64 + g * 8;
    Bt[ot][0] = *reinterpret_cast<const short8*>(wb);
    Bt[ot][1] = *reinterpret_cast<const short8*>(wb + 32);
  }

  // phase2: 1x1 projection via MFMA, A=weights B=xn -> D[ch][px]; packed b64 LDS writes
  short8 a0[3], a1[3];
#pragma unroll
  for (int j = 0; j < 3; ++j) {
    const int pt = wv + j * 8;
    const int p = pt * 16 + olocal;
    const int py = y0 + p / 18;
    const int px_ = x0 + p % 18;
    const bool vld = (pt < 21) && (p < 324) && ((unsigned)py < 256u) && ((unsigned)px_ < 256u);
    if (vld) {
      const short* ab = xnb + ((size_t)b * NPIX + py * WW + px_) * 64 + g * 8;
      a0[j] = *reinterpret_cast<const short8*>(ab);
      a1[j] = *reinterpret_cast<const short8*>(ab + 32);
    } else {
      a0[j] = zero8();
      a1[j] = zero8();
    }
  }
#pragma unroll
  for (int j = 0; j < 3; ++j) {
    const int pt = wv + j * 8;
    if (pt >= 21) continue;
    const int p2 = pt * 16 + olocal;   // this lane's pixel (D col = olocal)
#pragma unroll
    for (int ot = 0; ot < 4; ++ot) {
      f32x4 acc = {0.f, 0.f, 0.f, 0.f};
      acc = __builtin_amdgcn_mfma_f32_16x16x32_bf16(Bt[ot][0], a0[j], acc, 0, 0, 0);
      acc = __builtin_amdgcn_mfma_f32_16x16x32_bf16(Bt[ot][1], a1[j], acc, 0, 0, 0);
      uint2 st;
      st.x = pk2(acc[0], acc[1]);
      st.y = pk2(acc[2], acc[3]);
      *reinterpret_cast<uint2*>(&pr_s[p2 * PRS + ot * 16 + g * 4]) = st;
    }
  }
  __syncthreads();

  // phase3: depthwise 3x3; wave wv owns channels wv*8..wv*8+8
  const float* dmt = (t == 0) ? dw_q : (t == 1) ? dw_k : dw_v;
  float dmr[8][9];
#pragma unroll
  for (int u = 0; u < 8; ++u)
#pragma unroll
    for (int kk = 0; kk < 9; ++kk)
      dmr[u][kk] = dmt[(wv * 8 + u) * 9 + kk];
  bf16* ob = ((t == 0) ? qo : ko) + (size_t)b * CC * NPIX;
#pragma unroll
  for (int i = 0; i < 4; ++i) {
    const int pxl = lane + i * 64;
    const int oy = pxl >> 4, ox = pxl & 15;
    float acc8[8] = {0.f, 0.f, 0.f, 0.f, 0.f, 0.f, 0.f, 0.f};
#pragma unroll
    for (int ky = 0; ky < 3; ++ky)
#pragma unroll
      for (int kx = 0; kx < 3; ++kx) {
        const short8 pv = *reinterpret_cast<const short8*>(
            &pr_s[((oy + ky) * 18 + ox + kx) * PRS + wv * 8]);
        const int kk = ky * 3 + kx;
#pragma unroll
        for (int u = 0; u < 8; ++u)
          acc8[u] += dmr[u][kk] * bfs2f(pv[u]);
      }
    const int n = (ty * 16 + oy) * WW + tx * 16 + ox;
    if (t < 2) {
#pragma unroll
      for (int u = 0; u < 8; ++u)
        ob[(size_t)(wv * 8 + u) * NPIX + n] = f2bf(acc8[u]);
    } else {
      uint4 st = make_uint4(pk2(acc8[0], acc8[1]), pk2(acc8[2], acc8[3]),
                            pk2(acc8[4], acc8[5]), pk2(acc8[6], acc8[7]));
      *reinterpret_cast<uint4*>(&aov[((size_t)b * NPIX + n) * 64 + wv * 8]) = st;
    }
  }
}

// ---------------- partial logits + sumsq via MFMA, fragments straight from global
__global__ __launch_bounds__(256)
void k_logits(const bf16* __restrict__ q, const bf16* __restrict__ kk_,
              float* __restrict__ Spart, float* __restrict__ Qpart,
              float* __restrict__ Kpart) {
  const int tid = threadIdx.x;
  const int lane = tid & 63;
  const int wv = tid >> 6;            // 0..3
  const int bh = blockIdx.x >> 6;     // 0..31
  const int chunk = blockIdx.x & 63;  // 0..63
  const int row = lane & 15;
  const int g = lane >> 4;
  const short* qp = (const short*)q + (size_t)(bh * HD + row) * NPIX;
  const short* kp = (const short*)kk_ + (size_t)(bh * HD + row) * NPIX;
  const int n0 = chunk * 1024 + wv * 256 + g * 8;
  f32x4 s = {0.f, 0.f, 0.f, 0.f};
  f32x4 sq = {0.f, 0.f, 0.f, 0.f};
  f32x4 sk = {0.f, 0.f, 0.f, 0.f};
#pragma unroll
  for (int it = 0; it < 8; ++it) {
    const int n = n0 + it * 32;
    short8 qa = *reinterpret_cast<const short8*>(qp + n);
    short8 ka = *reinterpret_cast<const short8*>(kp + n);
    s  = __builtin_amdgcn_mfma_f32_16x16x32_bf16(qa, ka, s, 0, 0, 0);
    sq = __builtin_amdgcn_mfma_f32_16x16x32_bf16(qa, qa, sq, 0, 0, 0);
    sk = __builtin_amdgcn_mfma_f32_16x16x32_bf16(ka, ka, sk, 0, 0, 0);
  }
  const size_t tile = (size_t)blockIdx.x * 4 + wv;
  float* sp = Spart + tile * 256;
#pragma unroll
  for (int r = 0; r < 4; ++r)
    sp[(g * 4 + r) * 16 + row] = s[r];
  if ((row >> 2) == g) {
    Qpart[tile * 16 + row] = sq[row & 3];
    Kpart[tile * 16 + row] = sk[row & 3];
  }
}

// ---------------- reduce partials, normalize, softmax; emit block-diag bf16 attb
__global__ __launch_bounds__(256)
void k_softmax(const float* __restrict__ Spart, const float* __restrict__ Qpart,
               const float* __restrict__ Kpart, const float* __restrict__ temp,
               short* __restrict__ attb) {
  const int tid = threadIdx.x;
  const int bh = blockIdx.x;
  const int b = bh >> 2, h = bh & 3;
  const int i = tid >> 4, j = tid & 15;
  float S = 0.f, qs = 0.f, ks = 0.f;
  const size_t t0 = (size_t)bh * 256;
  for (int c = 0; c < 256; ++c) {
    S += Spart[(t0 + c) * 256 + tid];
    qs += Qpart[(t0 + c) * 16 + i];
    ks += Kpart[(t0 + c) * 16 + j];
  }
  float nq = fmaxf(sqrtf(qs), 1e-12f);
  float nk = fmaxf(sqrtf(ks), 1e-12f);
  float val = S / (nq * nk) * temp[h];
  float m = val;
  for (int d = 1; d < 16; d <<= 1) m = fmaxf(m, __shfl_xor(m, d));
  float e = __expf(val - m);
  float s = e;
  for (int d = 1; d < 16; d <<= 1) s += __shfl_xor(s, d);
  // diag block value
  attb[((size_t)b * 64 + h * 16 + i) * 64 + h * 16 + j] = f2bfs(e / s);
  // zero the off-diag cells of this bh's 16-row strip (disjoint across blocks)
#pragma unroll
  for (int mq = 0; mq < 4; ++mq) {
    const int idx = tid * 4 + mq;          // 0..1023
    const int r = idx >> 6, c = idx & 63;
    if ((c >> 4) != h)
      attb[((size_t)b * 64 + h * 16 + r) * 64 + c] = 0;
  }
}

// ---------------- fused: att_out = Attb @ v (block-diag GEMM) -> LDS; conv3x3 + res16
__global__ __launch_bounds__(512)
void k_attf(const short* __restrict__ attb, const short* __restrict__ vao,
            const short* __restrict__ wcpb, const short* __restrict__ res16,
            float* __restrict__ out) {
  __shared__ short ao_s[336 * PRS];  // att_out halo tile, [halo pix][64ch]
  const int tid = threadIdx.x;
  const int lane = tid & 63;
  const int wv = tid >> 6;          // 0..7
  const int olocal = lane & 15;
  const int g = lane >> 4;
  const int tx = blockIdx.x & 15, ty = (blockIdx.x >> 4) & 15, b = blockIdx.x >> 8;
  const int x0 = tx * 16 - 1, y0 = ty * 16 - 1;

  // phase A: att_out for 324 halo pixels via MFMA (A=attb rows, B=v pixel-major)
  {
    short8 AT[4][2];
#pragma unroll
    for (int ot = 0; ot < 4; ++ot) {
      const short* ab = attb + ((size_t)b * 64 + ot * 16 + olocal) * 64 + g * 8;
      AT[ot][0] = *reinterpret_cast<const short8*>(ab);
      AT[ot][1] = *reinterpret_cast<const short8*>(ab + 32);
    }
#pragma unroll
    for (int j = 0; j < 3; ++j) {
      const int pt = wv + j * 8;
      if (pt >= 21) continue;
      const int p = pt * 16 + olocal;
      const int py = y0 + p / 18;
      const int px_ = x0 + p % 18;
      const bool vld = (p < 324) && ((unsigned)py < 256u) && ((unsigned)px_ < 256u);
      short8 b0 = zero8(), b1 = zero8();
      if (vld) {
        const short* vp = vao + ((size_t)b * NPIX + py * WW + px_) * 64 + g * 8;
        b0 = *reinterpret_cast<const short8*>(vp);
        b1 = *reinterpret_cast<const short8*>(vp + 32);
      }
#pragma unroll
      for (int ot = 0; ot < 4; ++ot) {
        f32x4 acc = {0.f, 0.f, 0.f, 0.f};
        acc = __builtin_amdgcn_mfma_f32_16x16x32_bf16(AT[ot][0], b0, acc, 0, 0, 0);
        acc = __builtin_amdgcn_mfma_f32_16x16x32_bf16(AT[ot][1], b1, acc, 0, 0, 0);
        uint2 st;
        st.x = pk2(acc[0], acc[1]);
        st.y = pk2(acc[2], acc[3]);
        *reinterpret_cast<uint2*>(&ao_s[p * PRS + ot * 16 + g * 4]) = st;
      }
    }
  }
  __syncthreads();

  // phase B: conv3x3 via MFMA (A=wcp taps, B=att_out halo from LDS) + res16 seed
  short8 WA[9][2];
#pragma unroll
  for (int kk = 0; kk < 9; ++kk) {
    const short* wb = wcpb + (kk * 16 + olocal) * 64 + g * 8;
    WA[kk][0] = *reinterpret_cast<const short8*>(wb);
    WA[kk][1] = *reinterpret_cast<const short8*>(wb + 32);
  }
#pragma unroll
  for (int s = 0; s < 2; ++s) {
    const int oy = wv * 2 + s;      // 0..15
    const int n0 = (ty * 16 + oy) * WW + tx * 16;
    uint2 rv = *reinterpret_cast<const uint2*>(
        &res16[((size_t)b * NPIX + n0 + olocal) * 16 + g * 4]);
    f32x4 acc;
    acc[0] = __uint_as_float(rv.x << 16);
    acc[1] = __uint_as_float(rv.x & 0xffff0000u);
    acc[2] = __uint_as_float(rv.y << 16);
    acc[3] = __uint_as_float(rv.y & 0xffff0000u);
#pragma unroll
    for (int ky = 0; ky < 3; ++ky)
#pragma unroll
      for (int kx = 0; kx < 3; ++kx) {
        const int hp = (oy + ky) * 18 + olocal + kx;
        short8 b0 = *reinterpret_cast<const short8*>(&ao_s[hp * PRS + g * 8]);
        short8 b1 = *reinterpret_cast<const short8*>(&ao_s[hp * PRS + 32 + g * 8]);
        acc = __builtin_amdgcn_mfma_f32_16x16x32_bf16(WA[ky * 3 + kx][0], b0, acc, 0, 0, 0);
        acc = __builtin_amdgcn_mfma_f32_16x16x32_bf16(WA[ky * 3 + kx][1], b1, acc, 0, 0, 0);
      }
    float* op = out + ((size_t)b * 16 + g * 4) * NPIX + n0 + olocal;
    op[0] = acc[0];
    op[NPIX] = acc[1];
    op[2 * NPIX] = acc[2];
    op[3 * NPIX] = acc[3];
  }
}

extern "C" void kernel_launch(void* const* d_in, const int* in_sizes, int n_in,
                              void* d_out, int out_size, void* d_ws, size_t ws_size,
                              hipStream_t stream) {
  const float* x      = (const float*)d_in[0];
  const float* ln_w   = (const float*)d_in[1];
  const float* ln_b   = (const float*)d_in[2];
  const float* w_q    = (const float*)d_in[3];
  const float* w_k    = (const float*)d_in[4];
  const float* w_v    = (const float*)d_in[5];
  const float* dw_q   = (const float*)d_in[6];
  const float* dw_k   = (const float*)d_in[7];
  const float* dw_v   = (const float*)d_in[8];
  const float* w_proj = (const float*)d_in[9];
  const float* w_comp = (const float*)d_in[10];
  const float* temp   = (const float*)d_in[11];
  float* out = (float*)d_out;

  const size_t SPX = (size_t)BB * NPIX;   // 524288 pixels
  short* xnb   = (short*)d_ws;            // SPX*64  (67 MB) pixel-major LN'd x
  short* qb    = xnb + SPX * 64;          // planar bf16 q
  short* kb    = qb + SPX * 64;           // planar bf16 k
  short* aov   = kb + SPX * 64;           // pixel-major v
  short* res16 = aov + SPX * 64;          // SPX*16 (16 MB)
  short* wcpb  = res16 + SPX * 16;        // 9216
  short* wqkvb = wcpb + 9216;             // 12288
  short* wcb   = wqkvb + 12288;           // 1024
  short* attb  = wcb + 1024;              // 8*64*64 bf16 block-diag attn
  float* Spart = (float*)(attb + 8 * 64 * 64 + 512);  // 32*256*256 f32 (8 MB)
  float* Qpart = Spart + 32 * 256 * 256;
  float* Kpart = Qpart + 32 * 256 * 16;

  k_prep<<<52, 256, 0, stream>>>(w_comp, w_proj, w_q, w_k, w_v, wcpb, wqkvb, wcb);
  k_ln<<<2048, 256, 0, stream>>>(x, ln_w, ln_b, xnb);
  dim3 gqkv(2048, 3);
  k_qkv<<<gqkv, 512, 0, stream>>>(xnb, wqkvb, wcb, dw_q, dw_k, dw_v,
                                  (bf16*)qb, (bf16*)kb, aov, res16);
  k_logits<<<2048, 256, 0, stream>>>((const bf16*)qb, (const bf16*)kb, Spart, Qpart, Kpart);
  k_softmax<<<32, 256, 0, stream>>>(Spart, Qpart, Kpart, temp, attb);
  k_attf<<<2048, 512, 0, stream>>>(attb, aov, wcpb, res16, out);
}